// Round 1
// baseline (3135.503 us; speedup 1.0000x reference)
//
#include <hip/hip_runtime.h>
#include <hip/hip_bf16.h>
#include <cmath>

// Problem dims (fixed)
#define BATCH 4
#define SEQ 512
#define TOK (BATCH*SEQ)       // 2048
#define DMODEL 768
#define EDIM 1536
#define TWOE 3072
#define RDIM 48
#define NSTATE 16
#define RN2 80                // R + 2N
#define CONVK 4

#define EPI_STORE 0
#define EPI_BIAS 1
#define EPI_BIAS_SOFTPLUS 2
#define EPI_ADD 3

// C[m,n] = sum_k A[m*lda+k] * W[n*ldw+k]  (+ epilogue)
template<int EPI>
__global__ __launch_bounds__(256) void gemm_tn(
    const float* __restrict__ A, int lda,
    const float* __restrict__ W, int ldw,
    const float* __restrict__ bias,
    float* __restrict__ C, int ldc,
    int M, int Nn, int Kk) {
  __shared__ float As[16][68];   // [k][m], row stride 68 floats (272B = 17*16, keeps 16B align)
  __shared__ float Bs[16][68];   // [k][n]
  const int tid = threadIdx.x;
  const int m0 = blockIdx.y * 64, n0 = blockIdx.x * 64;
  const int lr = tid >> 2;          // 0..63
  const int lc = (tid & 3) << 2;    // 0,4,8,12
  const int ty = tid >> 4, tx = tid & 15;
  float acc[4][4] = {};

  for (int k0 = 0; k0 < Kk; k0 += 16) {
    {
      int m = m0 + lr;
      float4 v = make_float4(0.f, 0.f, 0.f, 0.f);
      if (m < M) v = *(const float4*)(A + (size_t)m * lda + k0 + lc);
      As[lc + 0][lr] = v.x; As[lc + 1][lr] = v.y;
      As[lc + 2][lr] = v.z; As[lc + 3][lr] = v.w;
    }
    {
      int nn = n0 + lr;
      float4 v = make_float4(0.f, 0.f, 0.f, 0.f);
      if (nn < Nn) v = *(const float4*)(W + (size_t)nn * ldw + k0 + lc);
      Bs[lc + 0][lr] = v.x; Bs[lc + 1][lr] = v.y;
      Bs[lc + 2][lr] = v.z; Bs[lc + 3][lr] = v.w;
    }
    __syncthreads();
#pragma unroll
    for (int kk = 0; kk < 16; ++kk) {
      float av[4], bv[4];
#pragma unroll
      for (int i = 0; i < 4; ++i) av[i] = As[kk][ty * 4 + i];
#pragma unroll
      for (int j = 0; j < 4; ++j) bv[j] = Bs[kk][tx * 4 + j];
#pragma unroll
      for (int i = 0; i < 4; ++i)
#pragma unroll
        for (int j = 0; j < 4; ++j)
          acc[i][j] += av[i] * bv[j];
    }
    __syncthreads();
  }

#pragma unroll
  for (int i = 0; i < 4; ++i) {
    int m = m0 + ty * 4 + i;
    if (m >= M) continue;
#pragma unroll
    for (int j = 0; j < 4; ++j) {
      int nn = n0 + tx * 4 + j;
      if (nn >= Nn) continue;
      float v = acc[i][j];
      float* cp = C + (size_t)m * ldc + nn;
      if (EPI == EPI_BIAS) v += bias[nn];
      if (EPI == EPI_BIAS_SOFTPLUS) {
        v += bias[nn];
        v = (v > 20.f) ? v : log1pf(expf(v));
      }
      if (EPI == EPI_ADD) v += *cp;
      *cp = v;
    }
  }
}

// Per-token RMSNorm: o[t,:] = x[t,:] * rsqrt(mean(x^2)+eps) * w
__global__ __launch_bounds__(256) void rmsnorm_k(
    const float* __restrict__ x, const float* __restrict__ w,
    float* __restrict__ o, int D) {
  const int t = blockIdx.x;
  const float* row = x + (size_t)t * D;
  __shared__ float ls[8];
  const int lane = threadIdx.x & 63, wave = threadIdx.x >> 6;
  float s = 0.f;
  for (int i = threadIdx.x; i < D; i += 256) { float v = row[i]; s += v * v; }
  for (int off = 32; off; off >>= 1) s += __shfl_down(s, off);
  if (lane == 0) ls[wave] = s;
  __syncthreads();
  float tot = ls[0] + ls[1] + ls[2] + ls[3];
  float rs = rsqrtf(tot / (float)D + 1e-5f);
  for (int i = threadIdx.x; i < D; i += 256)
    o[(size_t)t * D + i] = row[i] * rs * w[i];
}

// Depthwise causal conv (K=4) + bias + silu. xc = xz[..., :E] (row stride 3072).
__global__ __launch_bounds__(256) void conv_silu_k(
    const float* __restrict__ xz, const float* __restrict__ cw,
    const float* __restrict__ cb, float* __restrict__ u) {
  const int idx = blockIdx.x * 256 + threadIdx.x;   // tok*E + e
  const int e = idx % EDIM;
  const int tok = idx / EDIM;
  const int tl = tok & (SEQ - 1);
  float acc = cb[e];
  const float* w = cw + e * CONVK;
#pragma unroll
  for (int j = 0; j < CONVK; ++j) {
    int tt = tl - (CONVK - 1) + j;
    if (tt >= 0) acc += xz[(size_t)(tok - (CONVK - 1) + j) * TWOE + e] * w[j];
  }
  float sil = acc / (1.f + __expf(-acc));
  u[idx] = sil;
}

// Selective scan. One 16-lane group per (b,e); lane = n.
// Writes gated y: y[t,e] = (sum_n h*C + u*D) * silu(res).  y may alias delta.
__global__ __launch_bounds__(256) void scan_k(
    const float* __restrict__ delta, const float* __restrict__ u,
    const float* __restrict__ xdbl, const float* __restrict__ xz,
    const float* __restrict__ A_log, const float* __restrict__ D_ssm,
    float* __restrict__ y) {
  const int g = blockIdx.x * 16 + (threadIdx.x >> 4);
  const int n = threadIdx.x & 15;
  const int b = g / EDIM, e = g % EDIM;
  const float A = -__expf(A_log[e * NSTATE + n]);
  const float Dv = D_ssm[e];
  float hstate = 0.f;
  const size_t base = (size_t)b * SEQ;
  for (int t = 0; t < SEQ; ++t) {
    const size_t tok = base + t;
    float dv = delta[tok * EDIM + e];
    float uv = u[tok * EDIM + e];
    float Bv = xdbl[tok * RN2 + RDIM + n];
    float Cv = xdbl[tok * RN2 + RDIM + NSTATE + n];
    hstate = __expf(dv * A) * hstate + (dv * uv) * Bv;
    float p = hstate * Cv;
    p += __shfl_xor(p, 1); p += __shfl_xor(p, 2);
    p += __shfl_xor(p, 4); p += __shfl_xor(p, 8);
    if (n == 0) {
      float res = xz[tok * TWOE + EDIM + e];
      float sil = res / (1.f + __expf(-res));
      y[tok * EDIM + e] = (p + uv * Dv) * sil;
    }
  }
}

// Final: rmsnorm(last token) -> dot with out_w -> sigmoid. One block per batch.
__global__ __launch_bounds__(256) void final_k(
    const float* __restrict__ h, const float* __restrict__ nw,
    const float* __restrict__ ow, const float* __restrict__ ob,
    float* __restrict__ out) {
  const int b = blockIdx.x;
  const float* row = h + ((size_t)(b * SEQ + SEQ - 1)) * DMODEL;
  __shared__ float ls[8];
  __shared__ float ls2[8];
  const int lane = threadIdx.x & 63, wave = threadIdx.x >> 6;
  float s = 0.f;
  for (int i = threadIdx.x; i < DMODEL; i += 256) { float v = row[i]; s += v * v; }
  for (int off = 32; off; off >>= 1) s += __shfl_down(s, off);
  if (lane == 0) ls[wave] = s;
  __syncthreads();
  float tot = ls[0] + ls[1] + ls[2] + ls[3];
  float rs = rsqrtf(tot / (float)DMODEL + 1e-5f);
  float d = 0.f;
  for (int i = threadIdx.x; i < DMODEL; i += 256)
    d += row[i] * rs * nw[i] * ow[i];
  for (int off = 32; off; off >>= 1) d += __shfl_down(d, off);
  if (lane == 0) ls2[wave] = d;
  __syncthreads();
  if (threadIdx.x == 0) {
    float dot = ls2[0] + ls2[1] + ls2[2] + ls2[3] + ob[0];
    out[b] = 1.f / (1.f + expf(-dot));
  }
}

extern "C" void kernel_launch(void* const* d_in, const int* in_sizes, int n_in,
                              void* d_out, int out_size, void* d_ws, size_t ws_size,
                              hipStream_t stream) {
  const float* x         = (const float*)d_in[0];
  const float* in_w      = (const float*)d_in[1];
  const float* in_b      = (const float*)d_in[2];
  const float* in_proj_w = (const float*)d_in[3];
  const float* conv_w    = (const float*)d_in[4];
  const float* conv_b    = (const float*)d_in[5];
  const float* xproj_w   = (const float*)d_in[6];
  const float* dtproj_w  = (const float*)d_in[7];
  const float* dtproj_b  = (const float*)d_in[8];
  const float* A_log     = (const float*)d_in[9];
  const float* D_ssm     = (const float*)d_in[10];
  const float* outproj_w = (const float*)d_in[11];
  const float* norm_w    = (const float*)d_in[12];
  const float* normf_w   = (const float*)d_in[13];
  const float* out_w     = (const float*)d_in[14];
  const float* out_b     = (const float*)d_in[15];
  float* out = (float*)d_out;
  float* ws  = (float*)d_ws;

  // Workspace layout (floats). delta doubles as gated-y (safe in-place in scan).
  float* h   = ws;                        // TOK*DMODEL
  float* xn  = h   + (size_t)TOK * DMODEL; // TOK*DMODEL
  float* xz  = xn  + (size_t)TOK * DMODEL; // TOK*TWOE
  float* u   = xz  + (size_t)TOK * TWOE;   // TOK*EDIM
  float* xdb = u   + (size_t)TOK * EDIM;   // TOK*RN2
  float* dl  = xdb + (size_t)TOK * RN2;    // TOK*EDIM  (delta, then gated y)

  dim3 blk(256);

  // h = x @ in_w.T + in_b   (M=2048, N=768, K=32)
  gemm_tn<EPI_BIAS><<<dim3(DMODEL / 64, TOK / 64), blk, 0, stream>>>(
      x, 32, in_w, 32, in_b, h, DMODEL, TOK, DMODEL, 32);

  for (int l = 0; l < 4; ++l) {
    rmsnorm_k<<<TOK, 256, 0, stream>>>(h, norm_w + l * DMODEL, xn, DMODEL);

    // xz = xn @ in_proj_w[l].T   (M=2048, N=3072, K=768)
    gemm_tn<EPI_STORE><<<dim3(TWOE / 64, TOK / 64), blk, 0, stream>>>(
        xn, DMODEL, in_proj_w + (size_t)l * TWOE * DMODEL, DMODEL, nullptr,
        xz, TWOE, TOK, TWOE, DMODEL);

    conv_silu_k<<<(TOK * EDIM) / 256, 256, 0, stream>>>(
        xz, conv_w + l * EDIM * CONVK, conv_b + l * EDIM, u);

    // x_dbl = u @ xproj_w[l].T   (M=2048, N=80, K=1536)
    gemm_tn<EPI_STORE><<<dim3((RN2 + 63) / 64, TOK / 64), blk, 0, stream>>>(
        u, EDIM, xproj_w + (size_t)l * RN2 * EDIM, EDIM, nullptr,
        xdb, RN2, TOK, RN2, EDIM);

    // delta = softplus(dt @ dtproj_w[l].T + dtproj_b[l])  (M=2048, N=1536, K=48)
    gemm_tn<EPI_BIAS_SOFTPLUS><<<dim3(EDIM / 64, TOK / 64), blk, 0, stream>>>(
        xdb, RN2, dtproj_w + (size_t)l * EDIM * RDIM, RDIM, dtproj_b + l * EDIM,
        dl, EDIM, TOK, EDIM, RDIM);

    // scan + gate: dl <- gated y (in-place over delta)
    scan_k<<<(BATCH * EDIM) / 16, 256, 0, stream>>>(
        dl, u, xdb, xz, A_log + (size_t)l * EDIM * NSTATE, D_ssm + l * EDIM, dl);

    // h += y @ outproj_w[l].T   (M=2048, N=768, K=1536)
    gemm_tn<EPI_ADD><<<dim3(DMODEL / 64, TOK / 64), blk, 0, stream>>>(
        dl, EDIM, outproj_w + (size_t)l * DMODEL * EDIM, EDIM, nullptr,
        h, DMODEL, TOK, DMODEL, EDIM);
  }

  final_k<<<BATCH, 256, 0, stream>>>(h, normf_w, out_w, out_b, out);
}

// Round 2
// 2102.202 us; speedup vs baseline: 1.4915x; 1.4915x over previous
//
#include <hip/hip_runtime.h>
#include <hip/hip_bf16.h>
#include <cmath>

// Problem dims (fixed)
#define BATCH 4
#define SEQ 512
#define TOK (BATCH*SEQ)       // 2048
#define DMODEL 768
#define EDIM 1536
#define TWOE 3072
#define RDIM 48
#define NSTATE 16
#define RN2 80                // R + 2N
#define CONVK 4

#define EPI_STORE 0
#define EPI_BIAS 1
#define EPI_BIAS_SOFTPLUS 2
#define EPI_ADD 3

// C[m,n] = sum_k A[m*lda+k] * W[n*ldw+k]  (+ epilogue)
template<int EPI>
__global__ __launch_bounds__(256) void gemm_tn(
    const float* __restrict__ A, int lda,
    const float* __restrict__ W, int ldw,
    const float* __restrict__ bias,
    float* __restrict__ C, int ldc,
    int M, int Nn, int Kk) {
  __shared__ float As[16][68];   // [k][m]
  __shared__ float Bs[16][68];   // [k][n]
  const int tid = threadIdx.x;
  const int m0 = blockIdx.y * 64, n0 = blockIdx.x * 64;
  const int lr = tid >> 2;          // 0..63
  const int lc = (tid & 3) << 2;    // 0,4,8,12
  const int ty = tid >> 4, tx = tid & 15;
  float acc[4][4] = {};

  for (int k0 = 0; k0 < Kk; k0 += 16) {
    {
      int m = m0 + lr;
      float4 v = make_float4(0.f, 0.f, 0.f, 0.f);
      if (m < M) v = *(const float4*)(A + (size_t)m * lda + k0 + lc);
      As[lc + 0][lr] = v.x; As[lc + 1][lr] = v.y;
      As[lc + 2][lr] = v.z; As[lc + 3][lr] = v.w;
    }
    {
      int nn = n0 + lr;
      float4 v = make_float4(0.f, 0.f, 0.f, 0.f);
      if (nn < Nn) v = *(const float4*)(W + (size_t)nn * ldw + k0 + lc);
      Bs[lc + 0][lr] = v.x; Bs[lc + 1][lr] = v.y;
      Bs[lc + 2][lr] = v.z; Bs[lc + 3][lr] = v.w;
    }
    __syncthreads();
#pragma unroll
    for (int kk = 0; kk < 16; ++kk) {
      float av[4], bv[4];
#pragma unroll
      for (int i = 0; i < 4; ++i) av[i] = As[kk][ty * 4 + i];
#pragma unroll
      for (int j = 0; j < 4; ++j) bv[j] = Bs[kk][tx * 4 + j];
#pragma unroll
      for (int i = 0; i < 4; ++i)
#pragma unroll
        for (int j = 0; j < 4; ++j)
          acc[i][j] += av[i] * bv[j];
    }
    __syncthreads();
  }

#pragma unroll
  for (int i = 0; i < 4; ++i) {
    int m = m0 + ty * 4 + i;
    if (m >= M) continue;
#pragma unroll
    for (int j = 0; j < 4; ++j) {
      int nn = n0 + tx * 4 + j;
      if (nn >= Nn) continue;
      float v = acc[i][j];
      float* cp = C + (size_t)m * ldc + nn;
      if (EPI == EPI_BIAS) v += bias[nn];
      if (EPI == EPI_BIAS_SOFTPLUS) {
        v += bias[nn];
        v = (v > 20.f) ? v : log1pf(expf(v));
      }
      if (EPI == EPI_ADD) v += *cp;
      *cp = v;
    }
  }
}

// Per-token RMSNorm
__global__ __launch_bounds__(256) void rmsnorm_k(
    const float* __restrict__ x, const float* __restrict__ w,
    float* __restrict__ o, int D) {
  const int t = blockIdx.x;
  const float* row = x + (size_t)t * D;
  __shared__ float ls[8];
  const int lane = threadIdx.x & 63, wave = threadIdx.x >> 6;
  float s = 0.f;
  for (int i = threadIdx.x; i < D; i += 256) { float v = row[i]; s += v * v; }
  for (int off = 32; off; off >>= 1) s += __shfl_down(s, off);
  if (lane == 0) ls[wave] = s;
  __syncthreads();
  float tot = ls[0] + ls[1] + ls[2] + ls[3];
  float rs = rsqrtf(tot / (float)D + 1e-5f);
  for (int i = threadIdx.x; i < D; i += 256)
    o[(size_t)t * D + i] = row[i] * rs * w[i];
}

// Depthwise causal conv (K=4) + bias + silu
__global__ __launch_bounds__(256) void conv_silu_k(
    const float* __restrict__ xz, const float* __restrict__ cw,
    const float* __restrict__ cb, float* __restrict__ u) {
  const int idx = blockIdx.x * 256 + threadIdx.x;   // tok*E + e
  const int e = idx % EDIM;
  const int tok = idx / EDIM;
  const int tl = tok & (SEQ - 1);
  float acc = cb[e];
  const float* w = cw + e * CONVK;
#pragma unroll
  for (int j = 0; j < CONVK; ++j) {
    int tt = tl - (CONVK - 1) + j;
    if (tt >= 0) acc += xz[(size_t)(tok - (CONVK - 1) + j) * TWOE + e] * w[j];
  }
  float sil = acc / (1.f + __expf(-acc));
  u[idx] = sil;
}

// Selective scan, register-batched over T_U timesteps.
// One 16-lane group per (b,e); lane = n.  y aliases delta (no restrict on
// those two so the compiler keeps load/store order).
#define T_U 8
__global__ __launch_bounds__(256) void scan_k(
    const float* delta, const float* __restrict__ u,
    const float* __restrict__ xdbl, const float* __restrict__ xz,
    const float* __restrict__ A_log, const float* __restrict__ D_ssm,
    float* y) {
  const int g = blockIdx.x * 16 + (threadIdx.x >> 4);
  const int n = threadIdx.x & 15;
  const int b = g / EDIM, e = g % EDIM;
  const float A = -__expf(A_log[e * NSTATE + n]);
  const float Dv = D_ssm[e];
  float hstate = 0.f;
  const size_t base = (size_t)b * SEQ;
  for (int t0 = 0; t0 < SEQ; t0 += T_U) {
    float dv[T_U], uv[T_U], Bv[T_U], Cv[T_U], resv[T_U];
#pragma unroll
    for (int j = 0; j < T_U; ++j) {
      const size_t tok = base + t0 + j;
      dv[j]   = delta[tok * EDIM + e];
      uv[j]   = u[tok * EDIM + e];
      Bv[j]   = xdbl[tok * RN2 + RDIM + n];
      Cv[j]   = xdbl[tok * RN2 + RDIM + NSTATE + n];
      resv[j] = xz[tok * TWOE + EDIM + e];
    }
    float yv[T_U];
#pragma unroll
    for (int j = 0; j < T_U; ++j) {
      hstate = __expf(dv[j] * A) * hstate + (dv[j] * uv[j]) * Bv[j];
      float p = hstate * Cv[j];
      p += __shfl_xor(p, 1); p += __shfl_xor(p, 2);
      p += __shfl_xor(p, 4); p += __shfl_xor(p, 8);
      float sil = resv[j] / (1.f + __expf(-resv[j]));
      yv[j] = (p + uv[j] * Dv) * sil;
    }
    if (n == 0) {
#pragma unroll
      for (int j = 0; j < T_U; ++j)
        y[(base + t0 + j) * EDIM + e] = yv[j];
    }
  }
}

// Final: rmsnorm(last token) -> dot with out_w -> sigmoid.
__global__ __launch_bounds__(256) void final_k(
    const float* __restrict__ h, const float* __restrict__ nw,
    const float* __restrict__ ow, const float* __restrict__ ob,
    float* __restrict__ out) {
  const int b = blockIdx.x;
  const float* row = h + ((size_t)(b * SEQ + SEQ - 1)) * DMODEL;
  __shared__ float ls[8];
  __shared__ float ls2[8];
  const int lane = threadIdx.x & 63, wave = threadIdx.x >> 6;
  float s = 0.f;
  for (int i = threadIdx.x; i < DMODEL; i += 256) { float v = row[i]; s += v * v; }
  for (int off = 32; off; off >>= 1) s += __shfl_down(s, off);
  if (lane == 0) ls[wave] = s;
  __syncthreads();
  float tot = ls[0] + ls[1] + ls[2] + ls[3];
  float rs = rsqrtf(tot / (float)DMODEL + 1e-5f);
  float d = 0.f;
  for (int i = threadIdx.x; i < DMODEL; i += 256)
    d += row[i] * rs * nw[i] * ow[i];
  for (int off = 32; off; off >>= 1) d += __shfl_down(d, off);
  if (lane == 0) ls2[wave] = d;
  __syncthreads();
  if (threadIdx.x == 0) {
    float dot = ls2[0] + ls2[1] + ls2[2] + ls2[3] + ob[0];
    out[b] = 1.f / (1.f + expf(-dot));
  }
}

extern "C" void kernel_launch(void* const* d_in, const int* in_sizes, int n_in,
                              void* d_out, int out_size, void* d_ws, size_t ws_size,
                              hipStream_t stream) {
  const float* x         = (const float*)d_in[0];
  const float* in_w      = (const float*)d_in[1];
  const float* in_b      = (const float*)d_in[2];
  const float* in_proj_w = (const float*)d_in[3];
  const float* conv_w    = (const float*)d_in[4];
  const float* conv_b    = (const float*)d_in[5];
  const float* xproj_w   = (const float*)d_in[6];
  const float* dtproj_w  = (const float*)d_in[7];
  const float* dtproj_b  = (const float*)d_in[8];
  const float* A_log     = (const float*)d_in[9];
  const float* D_ssm     = (const float*)d_in[10];
  const float* outproj_w = (const float*)d_in[11];
  const float* norm_w    = (const float*)d_in[12];
  const float* normf_w   = (const float*)d_in[13];
  const float* out_w     = (const float*)d_in[14];
  const float* out_b     = (const float*)d_in[15];
  float* out = (float*)d_out;
  float* ws  = (float*)d_ws;

  float* h   = ws;                         // TOK*DMODEL
  float* xn  = h   + (size_t)TOK * DMODEL; // TOK*DMODEL
  float* xz  = xn  + (size_t)TOK * DMODEL; // TOK*TWOE
  float* u   = xz  + (size_t)TOK * TWOE;   // TOK*EDIM
  float* xdb = u   + (size_t)TOK * EDIM;   // TOK*RN2
  float* dl  = xdb + (size_t)TOK * RN2;    // TOK*EDIM  (delta, then gated y)

  dim3 blk(256);

  gemm_tn<EPI_BIAS><<<dim3(DMODEL / 64, TOK / 64), blk, 0, stream>>>(
      x, 32, in_w, 32, in_b, h, DMODEL, TOK, DMODEL, 32);

  for (int l = 0; l < 4; ++l) {
    rmsnorm_k<<<TOK, 256, 0, stream>>>(h, norm_w + l * DMODEL, xn, DMODEL);

    gemm_tn<EPI_STORE><<<dim3(TWOE / 64, TOK / 64), blk, 0, stream>>>(
        xn, DMODEL, in_proj_w + (size_t)l * TWOE * DMODEL, DMODEL, nullptr,
        xz, TWOE, TOK, TWOE, DMODEL);

    conv_silu_k<<<(TOK * EDIM) / 256, 256, 0, stream>>>(
        xz, conv_w + l * EDIM * CONVK, conv_b + l * EDIM, u);

    gemm_tn<EPI_STORE><<<dim3((RN2 + 63) / 64, TOK / 64), blk, 0, stream>>>(
        u, EDIM, xproj_w + (size_t)l * RN2 * EDIM, EDIM, nullptr,
        xdb, RN2, TOK, RN2, EDIM);

    gemm_tn<EPI_BIAS_SOFTPLUS><<<dim3(EDIM / 64, TOK / 64), blk, 0, stream>>>(
        xdb, RN2, dtproj_w + (size_t)l * EDIM * RDIM, RDIM, dtproj_b + l * EDIM,
        dl, EDIM, TOK, EDIM, RDIM);

    scan_k<<<(BATCH * EDIM) / 16, 256, 0, stream>>>(
        dl, u, xdb, xz, A_log + (size_t)l * EDIM * NSTATE, D_ssm + l * EDIM, dl);

    gemm_tn<EPI_ADD><<<dim3(DMODEL / 64, TOK / 64), blk, 0, stream>>>(
        dl, EDIM, outproj_w + (size_t)l * DMODEL * EDIM, EDIM, nullptr,
        h, DMODEL, TOK, DMODEL, EDIM);
  }

  final_k<<<BATCH, 256, 0, stream>>>(h, normf_w, out_w, out_b, out);
}

// Round 3
// 1293.505 us; speedup vs baseline: 2.4240x; 1.6252x over previous
//
#include <hip/hip_runtime.h>
#include <hip/hip_bf16.h>
#include <cmath>

#define BATCH 4
#define SEQ 512
#define TOK (BATCH*SEQ)       // 2048
#define DMODEL 768
#define EDIM 1536
#define TWOE 3072
#define RDIM 48
#define NSTATE 16
#define RN2 80
#define CONVK 4

#define EPI_STORE 0
#define EPI_BIAS 1
#define EPI_BIAS_SOFTPLUS 2
#define EPI_ADD 3

typedef short bf16x8 __attribute__((ext_vector_type(8)));
typedef float f32x4 __attribute__((ext_vector_type(4)));

__device__ __forceinline__ unsigned short f2bf(float f) {
  unsigned int u = __builtin_bit_cast(unsigned int, f);
  u = (u + 0x7FFFu + ((u >> 16) & 1u)) >> 16;
  return (unsigned short)u;
}

// ---------------- bf16 MFMA GEMM ----------------
// C[m,n] = sum_k A[m,k]*W[n,k]; A [M,K] bf16 row-major, W [N,K] bf16 row-major.
// BM,BN tiles; BK=64; 256 threads = 4 waves in 2x2.
// M%BM==0, N%BN==0, K%64==0 assumed.
template<int BM, int BN, int EPI>
__global__ __launch_bounds__(256) void gemm_mfma(
    const unsigned short* __restrict__ Abf,
    const unsigned short* __restrict__ Wbf,
    float* __restrict__ C, int ldc, int Kk) {
  constexpr int WM = BM / 2, WN = BN / 2;
  constexpr int IT = WM / 16, JT = WN / 16;
  __shared__ __align__(16) char smem[(BM + BN) * 128];
  char* ldsA = smem;
  char* ldsB = smem + BM * 128;

  const int tid = threadIdx.x;
  const int wid = tid >> 6, lane = tid & 63;
  const int m0 = blockIdx.y * BM, n0 = blockIdx.x * BN;
  const int wm = (wid >> 1) * WM, wn = (wid & 1) * WN;
  const int quad = lane >> 4, l15 = lane & 15;

  // staging: chunk = 8 rows x 64 k (1024 B). lane -> (row=lane>>3, slot=lane&7),
  // global k-chunk = slot ^ (row&7)  (XOR swizzle, matches reader below)
  const int srow = lane >> 3;
  const int kc = (lane & 7) ^ srow;
  const unsigned short* gA = Abf + (size_t)(m0 + srow) * Kk + kc * 8;
  const unsigned short* gB = Wbf + (size_t)(n0 + srow) * Kk + kc * 8;

  f32x4 acc[IT][JT] = {};

  for (int k0 = 0; k0 < Kk; k0 += 64) {
#pragma unroll
    for (int c = wid; c < BM / 8; c += 4)
      __builtin_amdgcn_global_load_lds(
          (const __attribute__((address_space(1))) void*)(gA + (size_t)(c * 8) * Kk + k0),
          (__attribute__((address_space(3))) void*)(ldsA + c * 1024), 16, 0, 0);
#pragma unroll
    for (int c = wid; c < BN / 8; c += 4)
      __builtin_amdgcn_global_load_lds(
          (const __attribute__((address_space(1))) void*)(gB + (size_t)(c * 8) * Kk + k0),
          (__attribute__((address_space(3))) void*)(ldsB + c * 1024), 16, 0, 0);
    asm volatile("s_waitcnt vmcnt(0)" ::: "memory");
    __syncthreads();
#pragma unroll
    for (int t = 0; t < 2; ++t) {
      const int cc = t * 4 + quad;
      bf16x8 av[IT], bv[JT];
#pragma unroll
      for (int i = 0; i < IT; ++i) {
        const int row = wm + i * 16 + l15;
        const int slot = cc ^ (row & 7);
        av[i] = *(const bf16x8*)(ldsA + row * 128 + slot * 16);
      }
#pragma unroll
      for (int j = 0; j < JT; ++j) {
        const int row = wn + j * 16 + l15;
        const int slot = cc ^ (row & 7);
        bv[j] = *(const bf16x8*)(ldsB + row * 128 + slot * 16);
      }
#pragma unroll
      for (int i = 0; i < IT; ++i)
#pragma unroll
        for (int j = 0; j < JT; ++j)
          acc[i][j] = __builtin_amdgcn_mfma_f32_16x16x32_bf16(av[i], bv[j], acc[i][j], 0, 0, 0);
    }
    __syncthreads();
  }

#pragma unroll
  for (int i = 0; i < IT; ++i) {
#pragma unroll
    for (int r = 0; r < 4; ++r) {
      const int m = m0 + wm + i * 16 + quad * 4 + r;
      float* crow = C + (size_t)m * ldc + n0 + wn;
#pragma unroll
      for (int j = 0; j < JT; ++j) {
        const int n = j * 16 + l15;
        float v = acc[i][j][r];
        if (EPI == EPI_ADD) v += crow[n];
        crow[n] = v;
      }
    }
  }
}

// ---------------- fp32 tiled GEMM (small shapes) ----------------
template<int EPI>
__global__ __launch_bounds__(256) void gemm_tn(
    const float* __restrict__ A, int lda,
    const float* __restrict__ W, int ldw,
    const float* __restrict__ bias,
    float* __restrict__ C, int ldc,
    int M, int Nn, int Kk) {
  __shared__ float As[16][68];
  __shared__ float Bs[16][68];
  const int tid = threadIdx.x;
  const int m0 = blockIdx.y * 64, n0 = blockIdx.x * 64;
  const int lr = tid >> 2;
  const int lc = (tid & 3) << 2;
  const int ty = tid >> 4, tx = tid & 15;
  float acc[4][4] = {};

  for (int k0 = 0; k0 < Kk; k0 += 16) {
    {
      int m = m0 + lr;
      float4 v = make_float4(0.f, 0.f, 0.f, 0.f);
      if (m < M) v = *(const float4*)(A + (size_t)m * lda + k0 + lc);
      As[lc + 0][lr] = v.x; As[lc + 1][lr] = v.y;
      As[lc + 2][lr] = v.z; As[lc + 3][lr] = v.w;
    }
    {
      int nn = n0 + lr;
      float4 v = make_float4(0.f, 0.f, 0.f, 0.f);
      if (nn < Nn) v = *(const float4*)(W + (size_t)nn * ldw + k0 + lc);
      Bs[lc + 0][lr] = v.x; Bs[lc + 1][lr] = v.y;
      Bs[lc + 2][lr] = v.z; Bs[lc + 3][lr] = v.w;
    }
    __syncthreads();
#pragma unroll
    for (int kk = 0; kk < 16; ++kk) {
      float av[4], bv[4];
#pragma unroll
      for (int i = 0; i < 4; ++i) av[i] = As[kk][ty * 4 + i];
#pragma unroll
      for (int j = 0; j < 4; ++j) bv[j] = Bs[kk][tx * 4 + j];
#pragma unroll
      for (int i = 0; i < 4; ++i)
#pragma unroll
        for (int j = 0; j < 4; ++j)
          acc[i][j] += av[i] * bv[j];
    }
    __syncthreads();
  }

#pragma unroll
  for (int i = 0; i < 4; ++i) {
    int m = m0 + ty * 4 + i;
    if (m >= M) continue;
#pragma unroll
    for (int j = 0; j < 4; ++j) {
      int nn = n0 + tx * 4 + j;
      if (nn >= Nn) continue;
      float v = acc[i][j];
      float* cp = C + (size_t)m * ldc + nn;
      if (EPI == EPI_BIAS) v += bias[nn];
      if (EPI == EPI_BIAS_SOFTPLUS) {
        v += bias[nn];
        v = (v > 20.f) ? v : log1pf(expf(v));
      }
      if (EPI == EPI_ADD) v += *cp;
      *cp = v;
    }
  }
}

// fp32 -> bf16 cast, 4 elems/thread. n % 4 == 0.
__global__ __launch_bounds__(256) void cast_bf16_k(
    const float* __restrict__ w, unsigned short* __restrict__ o, int n) {
  int i = (blockIdx.x * 256 + threadIdx.x) * 4;
  if (i >= n) return;
  float4 v = *(const float4*)(w + i);
  ushort4 r;
  r.x = f2bf(v.x); r.y = f2bf(v.y); r.z = f2bf(v.z); r.w = f2bf(v.w);
  *(ushort4*)(o + i) = r;
}

// RMSNorm -> bf16 output
__global__ __launch_bounds__(256) void rmsnorm_k(
    const float* __restrict__ x, const float* __restrict__ w,
    unsigned short* __restrict__ o, int D) {
  const int t = blockIdx.x;
  const float* row = x + (size_t)t * D;
  __shared__ float ls[8];
  const int lane = threadIdx.x & 63, wave = threadIdx.x >> 6;
  float s = 0.f;
  for (int i = threadIdx.x; i < D; i += 256) { float v = row[i]; s += v * v; }
  for (int off = 32; off; off >>= 1) s += __shfl_down(s, off);
  if (lane == 0) ls[wave] = s;
  __syncthreads();
  float tot = ls[0] + ls[1] + ls[2] + ls[3];
  float rs = rsqrtf(tot / (float)D + 1e-5f);
  for (int i = threadIdx.x; i < D; i += 256)
    o[(size_t)t * D + i] = f2bf(row[i] * rs * w[i]);
}

// Depthwise causal conv (K=4) + bias + silu
__global__ __launch_bounds__(256) void conv_silu_k(
    const float* __restrict__ xz, const float* __restrict__ cw,
    const float* __restrict__ cb, float* __restrict__ u) {
  const int idx = blockIdx.x * 256 + threadIdx.x;
  const int e = idx % EDIM;
  const int tok = idx / EDIM;
  const int tl = tok & (SEQ - 1);
  float acc = cb[e];
  const float* w = cw + e * CONVK;
#pragma unroll
  for (int j = 0; j < CONVK; ++j) {
    int tt = tl - (CONVK - 1) + j;
    if (tt >= 0) acc += xz[(size_t)(tok - (CONVK - 1) + j) * TWOE + e] * w[j];
  }
  u[idx] = acc / (1.f + __expf(-acc));
}

// Selective scan, register-batched; writes gated y as bf16.
#define T_U 8
__global__ __launch_bounds__(256) void scan_k(
    const float* __restrict__ delta, const float* __restrict__ u,
    const float* __restrict__ xdbl, const float* __restrict__ xz,
    const float* __restrict__ A_log, const float* __restrict__ D_ssm,
    unsigned short* __restrict__ y) {
  const int g = blockIdx.x * 16 + (threadIdx.x >> 4);
  const int n = threadIdx.x & 15;
  const int b = g / EDIM, e = g % EDIM;
  const float A = -__expf(A_log[e * NSTATE + n]);
  const float Dv = D_ssm[e];
  float hstate = 0.f;
  const size_t base = (size_t)b * SEQ;
  for (int t0 = 0; t0 < SEQ; t0 += T_U) {
    float dv[T_U], uv[T_U], Bv[T_U], Cv[T_U], resv[T_U];
#pragma unroll
    for (int j = 0; j < T_U; ++j) {
      const size_t tok = base + t0 + j;
      dv[j]   = delta[tok * EDIM + e];
      uv[j]   = u[tok * EDIM + e];
      Bv[j]   = xdbl[tok * RN2 + RDIM + n];
      Cv[j]   = xdbl[tok * RN2 + RDIM + NSTATE + n];
      resv[j] = xz[tok * TWOE + EDIM + e];
    }
    float yv[T_U];
#pragma unroll
    for (int j = 0; j < T_U; ++j) {
      hstate = __expf(dv[j] * A) * hstate + (dv[j] * uv[j]) * Bv[j];
      float p = hstate * Cv[j];
      p += __shfl_xor(p, 1); p += __shfl_xor(p, 2);
      p += __shfl_xor(p, 4); p += __shfl_xor(p, 8);
      float sil = resv[j] / (1.f + __expf(-resv[j]));
      yv[j] = (p + uv[j] * Dv) * sil;
    }
    if (n == 0) {
#pragma unroll
      for (int j = 0; j < T_U; ++j)
        y[(base + t0 + j) * EDIM + e] = f2bf(yv[j]);
    }
  }
}

// Final: rmsnorm(last token) -> dot out_w -> sigmoid
__global__ __launch_bounds__(256) void final_k(
    const float* __restrict__ h, const float* __restrict__ nw,
    const float* __restrict__ ow, const float* __restrict__ ob,
    float* __restrict__ out) {
  const int b = blockIdx.x;
  const float* row = h + ((size_t)(b * SEQ + SEQ - 1)) * DMODEL;
  __shared__ float ls[8];
  __shared__ float ls2[8];
  const int lane = threadIdx.x & 63, wave = threadIdx.x >> 6;
  float s = 0.f;
  for (int i = threadIdx.x; i < DMODEL; i += 256) { float v = row[i]; s += v * v; }
  for (int off = 32; off; off >>= 1) s += __shfl_down(s, off);
  if (lane == 0) ls[wave] = s;
  __syncthreads();
  float tot = ls[0] + ls[1] + ls[2] + ls[3];
  float rs = rsqrtf(tot / (float)DMODEL + 1e-5f);
  float d = 0.f;
  for (int i = threadIdx.x; i < DMODEL; i += 256)
    d += row[i] * rs * nw[i] * ow[i];
  for (int off = 32; off; off >>= 1) d += __shfl_down(d, off);
  if (lane == 0) ls2[wave] = d;
  __syncthreads();
  if (threadIdx.x == 0) {
    float dot = ls2[0] + ls2[1] + ls2[2] + ls2[3] + ob[0];
    out[b] = 1.f / (1.f + expf(-dot));
  }
}

extern "C" void kernel_launch(void* const* d_in, const int* in_sizes, int n_in,
                              void* d_out, int out_size, void* d_ws, size_t ws_size,
                              hipStream_t stream) {
  const float* x         = (const float*)d_in[0];
  const float* in_w      = (const float*)d_in[1];
  const float* in_b      = (const float*)d_in[2];
  const float* in_proj_w = (const float*)d_in[3];
  const float* conv_w    = (const float*)d_in[4];
  const float* conv_b    = (const float*)d_in[5];
  const float* xproj_w   = (const float*)d_in[6];
  const float* dtproj_w  = (const float*)d_in[7];
  const float* dtproj_b  = (const float*)d_in[8];
  const float* A_log     = (const float*)d_in[9];
  const float* D_ssm     = (const float*)d_in[10];
  const float* outproj_w = (const float*)d_in[11];
  const float* norm_w    = (const float*)d_in[12];
  const float* normf_w   = (const float*)d_in[13];
  const float* out_w     = (const float*)d_in[14];
  const float* out_b     = (const float*)d_in[15];
  float* out = (float*)d_out;
  float* ws  = (float*)d_ws;

  // fp32 buffers
  float* h   = ws;                          // TOK*DMODEL
  float* xz  = h   + (size_t)TOK * DMODEL;  // TOK*TWOE
  float* u   = xz  + (size_t)TOK * TWOE;    // TOK*EDIM
  float* xdb = u   + (size_t)TOK * EDIM;    // TOK*RN2
  float* dl  = xdb + (size_t)TOK * RN2;     // TOK*EDIM
  // bf16 buffers (ushort)
  unsigned short* xn_bf = (unsigned short*)(dl + (size_t)TOK * EDIM);  // TOK*DMODEL
  unsigned short* y_bf  = xn_bf + (size_t)TOK * DMODEL;                // TOK*EDIM
  unsigned short* w_bf  = y_bf + (size_t)TOK * EDIM;                   // max 3072*768

  dim3 blk(256);

  gemm_tn<EPI_BIAS><<<dim3(DMODEL / 64, TOK / 64), blk, 0, stream>>>(
      x, 32, in_w, 32, in_b, h, DMODEL, TOK, DMODEL, 32);

  for (int l = 0; l < 4; ++l) {
    rmsnorm_k<<<TOK, 256, 0, stream>>>(h, norm_w + l * DMODEL, xn_bf, DMODEL);

    // cast in_proj_w[l] -> bf16
    cast_bf16_k<<<(TWOE * DMODEL / 4 + 255) / 256, 256, 0, stream>>>(
        in_proj_w + (size_t)l * TWOE * DMODEL, w_bf, TWOE * DMODEL);

    // xz = xn @ in_proj_w.T  (MFMA bf16, 128x128 tiles)
    gemm_mfma<128, 128, EPI_STORE><<<dim3(TWOE / 128, TOK / 128), blk, 0, stream>>>(
        xn_bf, w_bf, xz, TWOE, DMODEL);

    conv_silu_k<<<(TOK * EDIM) / 256, 256, 0, stream>>>(
        xz, conv_w + l * EDIM * CONVK, conv_b + l * EDIM, u);

    gemm_tn<EPI_STORE><<<dim3((RN2 + 63) / 64, TOK / 64), blk, 0, stream>>>(
        u, EDIM, xproj_w + (size_t)l * RN2 * EDIM, EDIM, nullptr,
        xdb, RN2, TOK, RN2, EDIM);

    gemm_tn<EPI_BIAS_SOFTPLUS><<<dim3(EDIM / 64, TOK / 64), blk, 0, stream>>>(
        xdb, RN2, dtproj_w + (size_t)l * EDIM * RDIM, RDIM, dtproj_b + l * EDIM,
        dl, EDIM, TOK, EDIM, RDIM);

    scan_k<<<(BATCH * EDIM) / 16, 256, 0, stream>>>(
        dl, u, xdb, xz, A_log + (size_t)l * EDIM * NSTATE, D_ssm + l * EDIM, y_bf);

    // cast outproj_w[l] -> bf16
    cast_bf16_k<<<(DMODEL * EDIM / 4 + 255) / 256, 256, 0, stream>>>(
        outproj_w + (size_t)l * DMODEL * EDIM, w_bf, DMODEL * EDIM);

    // h += y @ outproj_w.T  (MFMA bf16, 64x64 tiles for block count)
    gemm_mfma<64, 64, EPI_ADD><<<dim3(DMODEL / 64, TOK / 64), blk, 0, stream>>>(
        y_bf, w_bf, h, DMODEL, EDIM);
  }

  final_k<<<BATCH, 256, 0, stream>>>(h, normf_w, out_w, out_b, out);
}

// Round 4
// 1096.889 us; speedup vs baseline: 2.8585x; 1.1792x over previous
//
#include <hip/hip_runtime.h>
#include <hip/hip_bf16.h>
#include <cmath>

#define BATCH 4
#define SEQ 512
#define TOK (BATCH*SEQ)       // 2048
#define DMODEL 768
#define EDIM 1536
#define TWOE 3072
#define RDIM 48
#define NSTATE 16
#define RN2 80
#define CONVK 4
#define XSPLIT 6              // split-K factor for xproj

#define EPI_STORE 0
#define EPI_BIAS 1
#define EPI_BIAS_SOFTPLUS 2
#define EPI_ADD 3

typedef short bf16x8 __attribute__((ext_vector_type(8)));
typedef float f32x4 __attribute__((ext_vector_type(4)));

__device__ __forceinline__ unsigned short f2bf(float f) {
  unsigned int u = __builtin_bit_cast(unsigned int, f);
  u = (u + 0x7FFFu + ((u >> 16) & 1u)) >> 16;
  return (unsigned short)u;
}

// ---------------- bf16 MFMA GEMM ----------------
// C[m,n] = sum_k A[m,k]*W[n,k]; A [M,ldk] bf16, W [N,ldk] bf16 row-major.
// Kk = K span per z-slice (koff = blockIdx.z*Kk); ldk = row stride.
// NB: mask stores to n < Nvalid. zCstride: C offset per z (split-K partials).
template<int BM, int BN, int EPI, bool NB>
__global__ __launch_bounds__(256) void gemm_mfma(
    const unsigned short* __restrict__ Abf,
    const unsigned short* __restrict__ Wbf,
    float* __restrict__ C, int ldc, int Kk, int ldk,
    int Nvalid, size_t zCstride) {
  constexpr int WM = BM / 2, WN = BN / 2;
  constexpr int IT = WM / 16, JT = WN / 16;
  __shared__ __align__(16) char smem[(BM + BN) * 128];
  char* ldsA = smem;
  char* ldsB = smem + BM * 128;

  const int tid = threadIdx.x;
  const int wid = tid >> 6, lane = tid & 63;
  const int m0 = blockIdx.y * BM, n0 = blockIdx.x * BN;
  const int wm = (wid >> 1) * WM, wn = (wid & 1) * WN;
  const int quad = lane >> 4, l15 = lane & 15;

  const int srow = lane >> 3;
  const int kc = (lane & 7) ^ srow;
  const int koff = blockIdx.z * Kk;
  C += (size_t)blockIdx.z * zCstride;
  const unsigned short* gA = Abf + (size_t)(m0 + srow) * ldk + kc * 8 + koff;
  const unsigned short* gB = Wbf + (size_t)(n0 + srow) * ldk + kc * 8 + koff;

  f32x4 acc[IT][JT] = {};

  for (int k0 = 0; k0 < Kk; k0 += 64) {
#pragma unroll
    for (int c = wid; c < BM / 8; c += 4)
      __builtin_amdgcn_global_load_lds(
          (const __attribute__((address_space(1))) void*)(gA + (size_t)(c * 8) * ldk + k0),
          (__attribute__((address_space(3))) void*)(ldsA + c * 1024), 16, 0, 0);
#pragma unroll
    for (int c = wid; c < BN / 8; c += 4)
      __builtin_amdgcn_global_load_lds(
          (const __attribute__((address_space(1))) void*)(gB + (size_t)(c * 8) * ldk + k0),
          (__attribute__((address_space(3))) void*)(ldsB + c * 1024), 16, 0, 0);
    asm volatile("s_waitcnt vmcnt(0)" ::: "memory");
    __syncthreads();
#pragma unroll
    for (int t = 0; t < 2; ++t) {
      const int cc = t * 4 + quad;
      bf16x8 av[IT], bv[JT];
#pragma unroll
      for (int i = 0; i < IT; ++i) {
        const int row = wm + i * 16 + l15;
        const int slot = cc ^ (row & 7);
        av[i] = *(const bf16x8*)(ldsA + row * 128 + slot * 16);
      }
#pragma unroll
      for (int j = 0; j < JT; ++j) {
        const int row = wn + j * 16 + l15;
        const int slot = cc ^ (row & 7);
        bv[j] = *(const bf16x8*)(ldsB + row * 128 + slot * 16);
      }
#pragma unroll
      for (int i = 0; i < IT; ++i)
#pragma unroll
        for (int j = 0; j < JT; ++j)
          acc[i][j] = __builtin_amdgcn_mfma_f32_16x16x32_bf16(av[i], bv[j], acc[i][j], 0, 0, 0);
    }
    __syncthreads();
  }

#pragma unroll
  for (int i = 0; i < IT; ++i) {
#pragma unroll
    for (int r = 0; r < 4; ++r) {
      const int m = m0 + wm + i * 16 + quad * 4 + r;
      float* crow = C + (size_t)m * ldc + n0 + wn;
#pragma unroll
      for (int j = 0; j < JT; ++j) {
        const int n = j * 16 + l15;
        if (NB && (n0 + wn + n) >= Nvalid) continue;
        float v = acc[i][j][r];
        if (EPI == EPI_ADD) v += crow[n];
        crow[n] = v;
      }
    }
  }
}

// Sum XSPLIT partials into xdb.
__global__ __launch_bounds__(256) void reduce_part_k(
    const float* __restrict__ part, float* __restrict__ out) {
  int i = (blockIdx.x * 256 + threadIdx.x) * 4;
  if (i >= TOK * RN2) return;
  float4 s = *(const float4*)(part + i);
#pragma unroll
  for (int z = 1; z < XSPLIT; ++z) {
    float4 v = *(const float4*)(part + (size_t)z * TOK * RN2 + i);
    s.x += v.x; s.y += v.y; s.z += v.z; s.w += v.w;
  }
  *(float4*)(out + i) = s;
}

// ---------------- fp32 tiled GEMM (small shapes) ----------------
template<int EPI>
__global__ __launch_bounds__(256) void gemm_tn(
    const float* __restrict__ A, int lda,
    const float* __restrict__ W, int ldw,
    const float* __restrict__ bias,
    float* __restrict__ C, int ldc,
    int M, int Nn, int Kk) {
  __shared__ float As[16][68];
  __shared__ float Bs[16][68];
  const int tid = threadIdx.x;
  const int m0 = blockIdx.y * 64, n0 = blockIdx.x * 64;
  const int lr = tid >> 2;
  const int lc = (tid & 3) << 2;
  const int ty = tid >> 4, tx = tid & 15;
  float acc[4][4] = {};

  for (int k0 = 0; k0 < Kk; k0 += 16) {
    {
      int m = m0 + lr;
      float4 v = make_float4(0.f, 0.f, 0.f, 0.f);
      if (m < M) v = *(const float4*)(A + (size_t)m * lda + k0 + lc);
      As[lc + 0][lr] = v.x; As[lc + 1][lr] = v.y;
      As[lc + 2][lr] = v.z; As[lc + 3][lr] = v.w;
    }
    {
      int nn = n0 + lr;
      float4 v = make_float4(0.f, 0.f, 0.f, 0.f);
      if (nn < Nn) v = *(const float4*)(W + (size_t)nn * ldw + k0 + lc);
      Bs[lc + 0][lr] = v.x; Bs[lc + 1][lr] = v.y;
      Bs[lc + 2][lr] = v.z; Bs[lc + 3][lr] = v.w;
    }
    __syncthreads();
#pragma unroll
    for (int kk = 0; kk < 16; ++kk) {
      float av[4], bv[4];
#pragma unroll
      for (int i = 0; i < 4; ++i) av[i] = As[kk][ty * 4 + i];
#pragma unroll
      for (int j = 0; j < 4; ++j) bv[j] = Bs[kk][tx * 4 + j];
#pragma unroll
      for (int i = 0; i < 4; ++i)
#pragma unroll
        for (int j = 0; j < 4; ++j)
          acc[i][j] += av[i] * bv[j];
    }
    __syncthreads();
  }

#pragma unroll
  for (int i = 0; i < 4; ++i) {
    int m = m0 + ty * 4 + i;
    if (m >= M) continue;
#pragma unroll
    for (int j = 0; j < 4; ++j) {
      int nn = n0 + tx * 4 + j;
      if (nn >= Nn) continue;
      float v = acc[i][j];
      float* cp = C + (size_t)m * ldc + nn;
      if (EPI == EPI_BIAS) v += bias[nn];
      if (EPI == EPI_BIAS_SOFTPLUS) {
        v += bias[nn];
        v = (v > 20.f) ? v : log1pf(expf(v));
      }
      if (EPI == EPI_ADD) v += *cp;
      *cp = v;
    }
  }
}

// fp32 -> bf16 cast, 4 elems/thread. n % 4 == 0.
__global__ __launch_bounds__(256) void cast_bf16_k(
    const float* __restrict__ w, unsigned short* __restrict__ o, int n) {
  int i = (blockIdx.x * 256 + threadIdx.x) * 4;
  if (i >= n) return;
  float4 v = *(const float4*)(w + i);
  ushort4 r;
  r.x = f2bf(v.x); r.y = f2bf(v.y); r.z = f2bf(v.z); r.w = f2bf(v.w);
  *(ushort4*)(o + i) = r;
}

// RMSNorm -> bf16 output
__global__ __launch_bounds__(256) void rmsnorm_k(
    const float* __restrict__ x, const float* __restrict__ w,
    unsigned short* __restrict__ o, int D) {
  const int t = blockIdx.x;
  const float* row = x + (size_t)t * D;
  __shared__ float ls[8];
  const int lane = threadIdx.x & 63, wave = threadIdx.x >> 6;
  float s = 0.f;
  for (int i = threadIdx.x; i < D; i += 256) { float v = row[i]; s += v * v; }
  for (int off = 32; off; off >>= 1) s += __shfl_down(s, off);
  if (lane == 0) ls[wave] = s;
  __syncthreads();
  float tot = ls[0] + ls[1] + ls[2] + ls[3];
  float rs = rsqrtf(tot / (float)D + 1e-5f);
  for (int i = threadIdx.x; i < D; i += 256)
    o[(size_t)t * D + i] = f2bf(row[i] * rs * w[i]);
}

// Depthwise causal conv (K=4) + bias + silu; dual fp32/bf16 output.
__global__ __launch_bounds__(256) void conv_silu_k(
    const float* __restrict__ xz, const float* __restrict__ cw,
    const float* __restrict__ cb, float* __restrict__ u,
    unsigned short* __restrict__ ubf) {
  const int idx = blockIdx.x * 256 + threadIdx.x;
  const int e = idx % EDIM;
  const int tok = idx / EDIM;
  const int tl = tok & (SEQ - 1);
  float acc = cb[e];
  const float* w = cw + e * CONVK;
#pragma unroll
  for (int j = 0; j < CONVK; ++j) {
    int tt = tl - (CONVK - 1) + j;
    if (tt >= 0) acc += xz[(size_t)(tok - (CONVK - 1) + j) * TWOE + e] * w[j];
  }
  float sil = acc / (1.f + __expf(-acc));
  u[idx] = sil;
  ubf[idx] = f2bf(sil);
}

// Selective scan, LDS double-buffered staging.
// Block = 16 e-groups x 16 n-lanes (same b). Grid = BATCH * (EDIM/16).
__global__ __launch_bounds__(256) void scan_k(
    const float* __restrict__ delta, const float* __restrict__ u,
    const float* __restrict__ xdbl, const float* __restrict__ xz,
    const float* __restrict__ A_log, const float* __restrict__ D_ssm,
    unsigned short* __restrict__ y) {
  const int tid = threadIdx.x;
  const int g = tid >> 4, n = tid & 15;
  const int b = blockIdx.x / (EDIM / 16);
  const int e0 = (blockIdx.x % (EDIM / 16)) * 16;
  const int e = e0 + g;
  const float A = -__expf(A_log[e * NSTATE + n]);
  const float Dv = D_ssm[e];
  const size_t base = (size_t)b * SEQ;

  __shared__ float s_dv[2][8][16];
  __shared__ float s_uv[2][8][16];
  __shared__ float s_rs[2][8][16];
  __shared__ float s_B[2][8][16];
  __shared__ float s_C[2][8][16];

  // staging roles: 5 roles x 32 threads; each loads one float4 per iter
  const int role = tid >> 5;
  const int rt = (tid & 31) >> 2;      // t within batch 0..7
  const int rq = (tid & 3) * 4;        // float4 column offset

  const float* gp = nullptr; size_t stp = 0; float* ld0 = nullptr;
  if (role == 0) { gp = delta + (base + rt) * EDIM + e0 + rq; stp = 8 * (size_t)EDIM; ld0 = &s_dv[0][rt][rq]; }
  else if (role == 1) { gp = u + (base + rt) * EDIM + e0 + rq; stp = 8 * (size_t)EDIM; ld0 = &s_uv[0][rt][rq]; }
  else if (role == 2) { gp = xz + (base + rt) * TWOE + EDIM + e0 + rq; stp = 8 * (size_t)TWOE; ld0 = &s_rs[0][rt][rq]; }
  else if (role == 3) { gp = xdbl + (base + rt) * RN2 + RDIM + rq; stp = 8 * (size_t)RN2; ld0 = &s_B[0][rt][rq]; }
  else if (role == 4) { gp = xdbl + (base + rt) * RN2 + RDIM + NSTATE + rq; stp = 8 * (size_t)RN2; ld0 = &s_C[0][rt][rq]; }

  if (role < 5) {                        // prologue: fill buffer 0
    float4 v = *(const float4*)gp; gp += stp;
    *(float4*)ld0 = v;
  }

  float hstate = 0.f;
  unsigned short* yp = y + base * EDIM + e;
  for (int it = 0; it < SEQ / 8; ++it) {
    const int cur = it & 1;
    const bool hn = (it < SEQ / 8 - 1) && (role < 5);
    float4 nv;
    if (hn) { nv = *(const float4*)gp; gp += stp; }   // prefetch next batch
    __syncthreads();                                  // buffer `cur` ready
#pragma unroll
    for (int j = 0; j < 8; ++j) {
      float dv = s_dv[cur][j][g];
      float uv = s_uv[cur][j][g];
      float Bv = s_B[cur][j][n];
      float Cv = s_C[cur][j][n];
      hstate = __expf(dv * A) * hstate + (dv * uv) * Bv;
      float p = hstate * Cv;
      p += __shfl_xor(p, 1); p += __shfl_xor(p, 2);
      p += __shfl_xor(p, 4); p += __shfl_xor(p, 8);
      if (n == 0) {
        float rsv = s_rs[cur][j][g];
        float sil = rsv / (1.f + __expf(-rsv));
        yp[(size_t)(it * 8 + j) * EDIM] = f2bf((p + uv * Dv) * sil);
      }
    }
    if (hn) *(float4*)(ld0 + (cur ^ 1) * 128) = nv;   // fill other buffer
  }
}

// Final: rmsnorm(last token) -> dot out_w -> sigmoid
__global__ __launch_bounds__(256) void final_k(
    const float* __restrict__ h, const float* __restrict__ nw,
    const float* __restrict__ ow, const float* __restrict__ ob,
    float* __restrict__ out) {
  const int b = blockIdx.x;
  const float* row = h + ((size_t)(b * SEQ + SEQ - 1)) * DMODEL;
  __shared__ float ls[8];
  __shared__ float ls2[8];
  const int lane = threadIdx.x & 63, wave = threadIdx.x >> 6;
  float s = 0.f;
  for (int i = threadIdx.x; i < DMODEL; i += 256) { float v = row[i]; s += v * v; }
  for (int off = 32; off; off >>= 1) s += __shfl_down(s, off);
  if (lane == 0) ls[wave] = s;
  __syncthreads();
  float tot = ls[0] + ls[1] + ls[2] + ls[3];
  float rs = rsqrtf(tot / (float)DMODEL + 1e-5f);
  float d = 0.f;
  for (int i = threadIdx.x; i < DMODEL; i += 256)
    d += row[i] * rs * nw[i] * ow[i];
  for (int off = 32; off; off >>= 1) d += __shfl_down(d, off);
  if (lane == 0) ls2[wave] = d;
  __syncthreads();
  if (threadIdx.x == 0) {
    float dot = ls2[0] + ls2[1] + ls2[2] + ls2[3] + ob[0];
    out[b] = 1.f / (1.f + expf(-dot));
  }
}

extern "C" void kernel_launch(void* const* d_in, const int* in_sizes, int n_in,
                              void* d_out, int out_size, void* d_ws, size_t ws_size,
                              hipStream_t stream) {
  const float* x         = (const float*)d_in[0];
  const float* in_w      = (const float*)d_in[1];
  const float* in_b      = (const float*)d_in[2];
  const float* in_proj_w = (const float*)d_in[3];
  const float* conv_w    = (const float*)d_in[4];
  const float* conv_b    = (const float*)d_in[5];
  const float* xproj_w   = (const float*)d_in[6];
  const float* dtproj_w  = (const float*)d_in[7];
  const float* dtproj_b  = (const float*)d_in[8];
  const float* A_log     = (const float*)d_in[9];
  const float* D_ssm     = (const float*)d_in[10];
  const float* outproj_w = (const float*)d_in[11];
  const float* norm_w    = (const float*)d_in[12];
  const float* normf_w   = (const float*)d_in[13];
  const float* out_w     = (const float*)d_in[14];
  const float* out_b     = (const float*)d_in[15];
  float* out = (float*)d_out;
  float* ws  = (float*)d_ws;

  // fp32 buffers
  float* h    = ws;                            // TOK*DMODEL
  float* xz   = h + (size_t)TOK * DMODEL;      // TOK*TWOE
  float* u    = xz + (size_t)TOK * TWOE;       // TOK*EDIM
  float* xdb  = u + (size_t)TOK * EDIM;        // TOK*RN2
  float* dl   = xdb + (size_t)TOK * RN2;       // TOK*EDIM
  float* part = dl + (size_t)TOK * EDIM;       // XSPLIT*TOK*RN2
  // bf16 buffers
  unsigned short* xn_bf = (unsigned short*)(part + (size_t)XSPLIT * TOK * RN2);
  unsigned short* y_bf  = xn_bf + (size_t)TOK * DMODEL;
  unsigned short* u_bf  = y_bf + (size_t)TOK * EDIM;
  unsigned short* w_in  = u_bf + (size_t)TOK * EDIM;     // TWOE*DMODEL
  unsigned short* w_out = w_in + (size_t)TWOE * DMODEL;  // DMODEL*EDIM
  unsigned short* w_x   = w_out + (size_t)DMODEL * EDIM; // 128*EDIM (80 filled)

  dim3 blk(256);

  gemm_tn<EPI_BIAS><<<dim3(DMODEL / 64, TOK / 64), blk, 0, stream>>>(
      x, 32, in_w, 32, in_b, h, DMODEL, TOK, DMODEL, 32);

  for (int l = 0; l < 4; ++l) {
    rmsnorm_k<<<TOK, 256, 0, stream>>>(h, norm_w + l * DMODEL, xn_bf, DMODEL);

    cast_bf16_k<<<(TWOE * DMODEL / 4 + 255) / 256, 256, 0, stream>>>(
        in_proj_w + (size_t)l * TWOE * DMODEL, w_in, TWOE * DMODEL);

    // xz = xn @ in_proj_w.T  (MFMA, 128x128)
    gemm_mfma<128, 128, EPI_STORE, false><<<dim3(TWOE / 128, TOK / 128, 1), blk, 0, stream>>>(
        xn_bf, w_in, xz, TWOE, DMODEL, DMODEL, TWOE, 0);

    conv_silu_k<<<(TOK * EDIM) / 256, 256, 0, stream>>>(
        xz, conv_w + l * EDIM * CONVK, conv_b + l * EDIM, u, u_bf);

    // x_dbl = u @ xproj_w.T  (MFMA split-K into partials, then reduce)
    cast_bf16_k<<<(RN2 * EDIM / 4 + 255) / 256, 256, 0, stream>>>(
        xproj_w + (size_t)l * RN2 * EDIM, w_x, RN2 * EDIM);
    gemm_mfma<64, 64, EPI_STORE, true><<<dim3(2, TOK / 64, XSPLIT), blk, 0, stream>>>(
        u_bf, w_x, part, RN2, EDIM / XSPLIT, EDIM, RN2, (size_t)TOK * RN2);
    reduce_part_k<<<(TOK * RN2 / 4 + 255) / 256, 256, 0, stream>>>(part, xdb);

    // delta = softplus(dt @ dtproj_w.T + b)  (fp32)
    gemm_tn<EPI_BIAS_SOFTPLUS><<<dim3(EDIM / 64, TOK / 64), blk, 0, stream>>>(
        xdb, RN2, dtproj_w + (size_t)l * EDIM * RDIM, RDIM, dtproj_b + l * EDIM,
        dl, EDIM, TOK, EDIM, RDIM);

    scan_k<<<BATCH * (EDIM / 16), 256, 0, stream>>>(
        dl, u, xdb, xz, A_log + (size_t)l * EDIM * NSTATE, D_ssm + l * EDIM, y_bf);

    cast_bf16_k<<<(DMODEL * EDIM / 4 + 255) / 256, 256, 0, stream>>>(
        outproj_w + (size_t)l * DMODEL * EDIM, w_out, DMODEL * EDIM);

    // h += y @ outproj_w.T  (MFMA, 64x64)
    gemm_mfma<64, 64, EPI_ADD, false><<<dim3(DMODEL / 64, TOK / 64, 1), blk, 0, stream>>>(
        y_bf, w_out, h, DMODEL, EDIM, EDIM, DMODEL, 0);
  }

  final_k<<<BATCH, 256, 0, stream>>>(h, normf_w, out_w, out_b, out);
}

// Round 5
// 848.470 us; speedup vs baseline: 3.6955x; 1.2928x over previous
//
#include <hip/hip_runtime.h>
#include <hip/hip_bf16.h>
#include <cmath>

#define BATCH 4
#define SEQ 512
#define TOK (BATCH*SEQ)       // 2048
#define DMODEL 768
#define EDIM 1536
#define TWOE 3072
#define RDIM 48
#define NSTATE 16
#define RN2 80
#define CONVK 4
#define XSPLIT 6              // split-K factor for xproj
#define CH 8                  // scan chunks
#define CL (SEQ/CH)           // 64 steps per chunk

#define EPI_STORE 0
#define EPI_BIAS 1
#define EPI_BIAS_SOFTPLUS 2
#define EPI_ADD 3

typedef short bf16x8 __attribute__((ext_vector_type(8)));
typedef float f32x4 __attribute__((ext_vector_type(4)));

__device__ __forceinline__ unsigned short f2bf(float f) {
  unsigned int u = __builtin_bit_cast(unsigned int, f);
  u = (u + 0x7FFFu + ((u >> 16) & 1u)) >> 16;
  return (unsigned short)u;
}

// ---------------- bf16 MFMA GEMM ----------------
template<int BM, int BN, int EPI, bool NB>
__global__ __launch_bounds__(256) void gemm_mfma(
    const unsigned short* __restrict__ Abf,
    const unsigned short* __restrict__ Wbf,
    float* __restrict__ C, int ldc, int Kk, int ldk,
    int Nvalid, size_t zCstride) {
  constexpr int WM = BM / 2, WN = BN / 2;
  constexpr int IT = WM / 16, JT = WN / 16;
  __shared__ __align__(16) char smem[(BM + BN) * 128];
  char* ldsA = smem;
  char* ldsB = smem + BM * 128;

  const int tid = threadIdx.x;
  const int wid = tid >> 6, lane = tid & 63;
  const int m0 = blockIdx.y * BM, n0 = blockIdx.x * BN;
  const int wm = (wid >> 1) * WM, wn = (wid & 1) * WN;
  const int quad = lane >> 4, l15 = lane & 15;

  const int srow = lane >> 3;
  const int kc = (lane & 7) ^ srow;
  const int koff = blockIdx.z * Kk;
  C += (size_t)blockIdx.z * zCstride;
  const unsigned short* gA = Abf + (size_t)(m0 + srow) * ldk + kc * 8 + koff;
  const unsigned short* gB = Wbf + (size_t)(n0 + srow) * ldk + kc * 8 + koff;

  f32x4 acc[IT][JT] = {};

  for (int k0 = 0; k0 < Kk; k0 += 64) {
#pragma unroll
    for (int c = wid; c < BM / 8; c += 4)
      __builtin_amdgcn_global_load_lds(
          (const __attribute__((address_space(1))) void*)(gA + (size_t)(c * 8) * ldk + k0),
          (__attribute__((address_space(3))) void*)(ldsA + c * 1024), 16, 0, 0);
#pragma unroll
    for (int c = wid; c < BN / 8; c += 4)
      __builtin_amdgcn_global_load_lds(
          (const __attribute__((address_space(1))) void*)(gB + (size_t)(c * 8) * ldk + k0),
          (__attribute__((address_space(3))) void*)(ldsB + c * 1024), 16, 0, 0);
    asm volatile("s_waitcnt vmcnt(0)" ::: "memory");
    __syncthreads();
#pragma unroll
    for (int t = 0; t < 2; ++t) {
      const int cc = t * 4 + quad;
      bf16x8 av[IT], bv[JT];
#pragma unroll
      for (int i = 0; i < IT; ++i) {
        const int row = wm + i * 16 + l15;
        const int slot = cc ^ (row & 7);
        av[i] = *(const bf16x8*)(ldsA + row * 128 + slot * 16);
      }
#pragma unroll
      for (int j = 0; j < JT; ++j) {
        const int row = wn + j * 16 + l15;
        const int slot = cc ^ (row & 7);
        bv[j] = *(const bf16x8*)(ldsB + row * 128 + slot * 16);
      }
#pragma unroll
      for (int i = 0; i < IT; ++i)
#pragma unroll
        for (int j = 0; j < JT; ++j)
          acc[i][j] = __builtin_amdgcn_mfma_f32_16x16x32_bf16(av[i], bv[j], acc[i][j], 0, 0, 0);
    }
    __syncthreads();
  }

#pragma unroll
  for (int i = 0; i < IT; ++i) {
#pragma unroll
    for (int r = 0; r < 4; ++r) {
      const int m = m0 + wm + i * 16 + quad * 4 + r;
      float* crow = C + (size_t)m * ldc + n0 + wn;
#pragma unroll
      for (int j = 0; j < JT; ++j) {
        const int n = j * 16 + l15;
        if (NB && (n0 + wn + n) >= Nvalid) continue;
        float v = acc[i][j][r];
        if (EPI == EPI_ADD) v += crow[n];
        crow[n] = v;
      }
    }
  }
}

// Sum XSPLIT partials into xdb.
__global__ __launch_bounds__(256) void reduce_part_k(
    const float* __restrict__ part, float* __restrict__ out) {
  int i = (blockIdx.x * 256 + threadIdx.x) * 4;
  if (i >= TOK * RN2) return;
  float4 s = *(const float4*)(part + i);
#pragma unroll
  for (int z = 1; z < XSPLIT; ++z) {
    float4 v = *(const float4*)(part + (size_t)z * TOK * RN2 + i);
    s.x += v.x; s.y += v.y; s.z += v.z; s.w += v.w;
  }
  *(float4*)(out + i) = s;
}

// ---------------- fp32 tiled GEMM ----------------
template<int EPI>
__global__ __launch_bounds__(256) void gemm_tn(
    const float* __restrict__ A, int lda,
    const float* __restrict__ W, int ldw,
    const float* __restrict__ bias,
    float* __restrict__ C, int ldc,
    int M, int Nn, int Kk) {
  __shared__ float As[16][68];
  __shared__ float Bs[16][68];
  const int tid = threadIdx.x;
  const int m0 = blockIdx.y * 64, n0 = blockIdx.x * 64;
  const int lr = tid >> 2;
  const int lc = (tid & 3) << 2;
  const int ty = tid >> 4, tx = tid & 15;
  float acc[4][4] = {};

  for (int k0 = 0; k0 < Kk; k0 += 16) {
    {
      int m = m0 + lr;
      float4 v = make_float4(0.f, 0.f, 0.f, 0.f);
      if (m < M) v = *(const float4*)(A + (size_t)m * lda + k0 + lc);
      As[lc + 0][lr] = v.x; As[lc + 1][lr] = v.y;
      As[lc + 2][lr] = v.z; As[lc + 3][lr] = v.w;
    }
    {
      int nn = n0 + lr;
      float4 v = make_float4(0.f, 0.f, 0.f, 0.f);
      if (nn < Nn) v = *(const float4*)(W + (size_t)nn * ldw + k0 + lc);
      Bs[lc + 0][lr] = v.x; Bs[lc + 1][lr] = v.y;
      Bs[lc + 2][lr] = v.z; Bs[lc + 3][lr] = v.w;
    }
    __syncthreads();
#pragma unroll
    for (int kk = 0; kk < 16; ++kk) {
      float av[4], bv[4];
#pragma unroll
      for (int i = 0; i < 4; ++i) av[i] = As[kk][ty * 4 + i];
#pragma unroll
      for (int j = 0; j < 4; ++j) bv[j] = Bs[kk][tx * 4 + j];
#pragma unroll
      for (int i = 0; i < 4; ++i)
#pragma unroll
        for (int j = 0; j < 4; ++j)
          acc[i][j] += av[i] * bv[j];
    }
    __syncthreads();
  }

#pragma unroll
  for (int i = 0; i < 4; ++i) {
    int m = m0 + ty * 4 + i;
    if (m >= M) continue;
#pragma unroll
    for (int j = 0; j < 4; ++j) {
      int nn = n0 + tx * 4 + j;
      if (nn >= Nn) continue;
      float v = acc[i][j];
      float* cp = C + (size_t)m * ldc + nn;
      if (EPI == EPI_BIAS) v += bias[nn];
      if (EPI == EPI_BIAS_SOFTPLUS) {
        v += bias[nn];
        v = (v > 20.f) ? v : log1pf(expf(v));
      }
      if (EPI == EPI_ADD) v += *cp;
      *cp = v;
    }
  }
}

__global__ __launch_bounds__(256) void cast_bf16_k(
    const float* __restrict__ w, unsigned short* __restrict__ o, int n) {
  int i = (blockIdx.x * 256 + threadIdx.x) * 4;
  if (i >= n) return;
  float4 v = *(const float4*)(w + i);
  ushort4 r;
  r.x = f2bf(v.x); r.y = f2bf(v.y); r.z = f2bf(v.z); r.w = f2bf(v.w);
  *(ushort4*)(o + i) = r;
}

__global__ __launch_bounds__(256) void rmsnorm_k(
    const float* __restrict__ x, const float* __restrict__ w,
    unsigned short* __restrict__ o, int D) {
  const int t = blockIdx.x;
  const float* row = x + (size_t)t * D;
  __shared__ float ls[8];
  const int lane = threadIdx.x & 63, wave = threadIdx.x >> 6;
  float s = 0.f;
  for (int i = threadIdx.x; i < D; i += 256) { float v = row[i]; s += v * v; }
  for (int off = 32; off; off >>= 1) s += __shfl_down(s, off);
  if (lane == 0) ls[wave] = s;
  __syncthreads();
  float tot = ls[0] + ls[1] + ls[2] + ls[3];
  float rs = rsqrtf(tot / (float)D + 1e-5f);
  for (int i = threadIdx.x; i < D; i += 256)
    o[(size_t)t * D + i] = f2bf(row[i] * rs * w[i]);
}

__global__ __launch_bounds__(256) void conv_silu_k(
    const float* __restrict__ xz, const float* __restrict__ cw,
    const float* __restrict__ cb, float* __restrict__ u,
    unsigned short* __restrict__ ubf) {
  const int idx = blockIdx.x * 256 + threadIdx.x;
  const int e = idx % EDIM;
  const int tok = idx / EDIM;
  const int tl = tok & (SEQ - 1);
  float acc = cb[e];
  const float* w = cw + e * CONVK;
#pragma unroll
  for (int j = 0; j < CONVK; ++j) {
    int tt = tl - (CONVK - 1) + j;
    if (tt >= 0) acc += xz[(size_t)(tok - (CONVK - 1) + j) * TWOE + e] * w[j];
  }
  float sil = acc / (1.f + __expf(-acc));
  u[idx] = sil;
  ubf[idx] = f2bf(sil);
}

// ---------------- chunked selective scan ----------------
// Pass 1: per (b, chunk, e-group) local scan with h_in=0.
// Outputs hend and aprod at [((b*CH+c)*EDIM+e)*16+n].
__global__ __launch_bounds__(256) void scan_p1(
    const float* __restrict__ delta, const float* __restrict__ u,
    const float* __restrict__ xdbl, const float* __restrict__ A_log,
    float* __restrict__ hend, float* __restrict__ aprod) {
  const int tid = threadIdx.x;
  const int g = tid >> 4, n = tid & 15;
  const int nch = blockIdx.x & (CH - 1);
  const int rem = blockIdx.x >> 3;
  const int e0 = (rem % (EDIM / 16)) * 16;
  const int b = rem / (EDIM / 16);
  const int e = e0 + g;
  const float A = -__expf(A_log[e * NSTATE + n]);
  const size_t base = (size_t)b * SEQ + nch * CL;

  __shared__ float s_dv[2][8][16];
  __shared__ float s_uv[2][8][16];
  __shared__ float s_B[2][8][16];

  const int role = tid >> 5;
  const int rt = (tid & 31) >> 2;
  const int rq = (tid & 3) * 4;
  const float* gp = nullptr; size_t stp = 0; float* ld0 = nullptr;
  if (role == 0) { gp = delta + (base + rt) * EDIM + e0 + rq; stp = 8 * (size_t)EDIM; ld0 = &s_dv[0][rt][rq]; }
  else if (role == 1) { gp = u + (base + rt) * EDIM + e0 + rq; stp = 8 * (size_t)EDIM; ld0 = &s_uv[0][rt][rq]; }
  else if (role == 2) { gp = xdbl + (base + rt) * RN2 + RDIM + rq; stp = 8 * (size_t)RN2; ld0 = &s_B[0][rt][rq]; }
  if (role < 3) { float4 v = *(const float4*)gp; gp += stp; *(float4*)ld0 = v; }

  float h = 0.f, ap = 1.f;
  for (int it = 0; it < CL / 8; ++it) {
    const int cur = it & 1;
    const bool hn = (it < CL / 8 - 1) && (role < 3);
    float4 nv;
    if (hn) { nv = *(const float4*)gp; gp += stp; }
    __syncthreads();
#pragma unroll
    for (int j = 0; j < 8; ++j) {
      float dv = s_dv[cur][j][g];
      float uv = s_uv[cur][j][g];
      float Bv = s_B[cur][j][n];
      float dA = __expf(dv * A);
      h = dA * h + (dv * uv) * Bv;
      ap *= dA;
    }
    if (hn) *(float4*)(ld0 + (cur ^ 1) * 128) = nv;
  }
  size_t o = (((size_t)b * CH + nch) * EDIM + e) * NSTATE + n;
  hend[o] = h;
  aprod[o] = ap;
}

// Combine: prefix over chunks -> h_in per chunk.
__global__ __launch_bounds__(256) void scan_comb(
    const float* __restrict__ hend, const float* __restrict__ aprod,
    float* __restrict__ hin) {
  int i = blockIdx.x * 256 + threadIdx.x;      // (b*EDIM+e)*16+n
  if (i >= BATCH * EDIM * NSTATE) return;
  int b = i / (EDIM * NSTATE);
  int en = i % (EDIM * NSTATE);
  float he[CH], ap[CH];
#pragma unroll
  for (int c = 0; c < CH; ++c) {
    size_t o = ((size_t)(b * CH + c)) * EDIM * NSTATE + en;
    he[c] = hend[o]; ap[c] = aprod[o];
  }
  float hv = 0.f;
#pragma unroll
  for (int c = 0; c < CH; ++c) {
    size_t o = ((size_t)(b * CH + c)) * EDIM * NSTATE + en;
    hin[o] = hv;
    hv = he[c] + ap[c] * hv;
  }
}

// Pass 2: full scan seeded with h_in; emits gated y (bf16).
__global__ __launch_bounds__(256) void scan_p2(
    const float* __restrict__ delta, const float* __restrict__ u,
    const float* __restrict__ xdbl, const float* __restrict__ xz,
    const float* __restrict__ A_log, const float* __restrict__ D_ssm,
    const float* __restrict__ hin, unsigned short* __restrict__ y) {
  const int tid = threadIdx.x;
  const int g = tid >> 4, n = tid & 15;
  const int nch = blockIdx.x & (CH - 1);
  const int rem = blockIdx.x >> 3;
  const int e0 = (rem % (EDIM / 16)) * 16;
  const int b = rem / (EDIM / 16);
  const int e = e0 + g;
  const float A = -__expf(A_log[e * NSTATE + n]);
  const float Dv = D_ssm[e];
  const size_t base = (size_t)b * SEQ + nch * CL;

  __shared__ float s_dv[2][8][16];
  __shared__ float s_uv[2][8][16];
  __shared__ float s_rs[2][8][16];
  __shared__ float s_B[2][8][16];
  __shared__ float s_C[2][8][16];

  const int role = tid >> 5;
  const int rt = (tid & 31) >> 2;
  const int rq = (tid & 3) * 4;
  const float* gp = nullptr; size_t stp = 0; float* ld0 = nullptr;
  if (role == 0) { gp = delta + (base + rt) * EDIM + e0 + rq; stp = 8 * (size_t)EDIM; ld0 = &s_dv[0][rt][rq]; }
  else if (role == 1) { gp = u + (base + rt) * EDIM + e0 + rq; stp = 8 * (size_t)EDIM; ld0 = &s_uv[0][rt][rq]; }
  else if (role == 2) { gp = xz + (base + rt) * TWOE + EDIM + e0 + rq; stp = 8 * (size_t)TWOE; ld0 = &s_rs[0][rt][rq]; }
  else if (role == 3) { gp = xdbl + (base + rt) * RN2 + RDIM + rq; stp = 8 * (size_t)RN2; ld0 = &s_B[0][rt][rq]; }
  else if (role == 4) { gp = xdbl + (base + rt) * RN2 + RDIM + NSTATE + rq; stp = 8 * (size_t)RN2; ld0 = &s_C[0][rt][rq]; }
  if (role < 5) { float4 v = *(const float4*)gp; gp += stp; *(float4*)ld0 = v; }

  float hstate = hin[(((size_t)b * CH + nch) * EDIM + e) * NSTATE + n];
  unsigned short* yp = y + base * EDIM + e;
  for (int it = 0; it < CL / 8; ++it) {
    const int cur = it & 1;
    const bool hn = (it < CL / 8 - 1) && (role < 5);
    float4 nv;
    if (hn) { nv = *(const float4*)gp; gp += stp; }
    __syncthreads();
#pragma unroll
    for (int j = 0; j < 8; ++j) {
      float dv = s_dv[cur][j][g];
      float uv = s_uv[cur][j][g];
      float Bv = s_B[cur][j][n];
      float Cv = s_C[cur][j][n];
      hstate = __expf(dv * A) * hstate + (dv * uv) * Bv;
      float p = hstate * Cv;
      p += __shfl_xor(p, 1); p += __shfl_xor(p, 2);
      p += __shfl_xor(p, 4); p += __shfl_xor(p, 8);
      if (n == 0) {
        float rsv = s_rs[cur][j][g];
        float sil = rsv / (1.f + __expf(-rsv));
        yp[(size_t)(it * 8 + j) * EDIM] = f2bf((p + uv * Dv) * sil);
      }
    }
    if (hn) *(float4*)(ld0 + (cur ^ 1) * 128) = nv;
  }
}

// Final: rmsnorm(last token) -> dot out_w -> sigmoid
__global__ __launch_bounds__(256) void final_k(
    const float* __restrict__ h, const float* __restrict__ nw,
    const float* __restrict__ ow, const float* __restrict__ ob,
    float* __restrict__ out) {
  const int b = blockIdx.x;
  const float* row = h + ((size_t)(b * SEQ + SEQ - 1)) * DMODEL;
  __shared__ float ls[8];
  __shared__ float ls2[8];
  const int lane = threadIdx.x & 63, wave = threadIdx.x >> 6;
  float s = 0.f;
  for (int i = threadIdx.x; i < DMODEL; i += 256) { float v = row[i]; s += v * v; }
  for (int off = 32; off; off >>= 1) s += __shfl_down(s, off);
  if (lane == 0) ls[wave] = s;
  __syncthreads();
  float tot = ls[0] + ls[1] + ls[2] + ls[3];
  float rs = rsqrtf(tot / (float)DMODEL + 1e-5f);
  float d = 0.f;
  for (int i = threadIdx.x; i < DMODEL; i += 256)
    d += row[i] * rs * nw[i] * ow[i];
  for (int off = 32; off; off >>= 1) d += __shfl_down(d, off);
  if (lane == 0) ls2[wave] = d;
  __syncthreads();
  if (threadIdx.x == 0) {
    float dot = ls2[0] + ls2[1] + ls2[2] + ls2[3] + ob[0];
    out[b] = 1.f / (1.f + expf(-dot));
  }
}

extern "C" void kernel_launch(void* const* d_in, const int* in_sizes, int n_in,
                              void* d_out, int out_size, void* d_ws, size_t ws_size,
                              hipStream_t stream) {
  const float* x         = (const float*)d_in[0];
  const float* in_w      = (const float*)d_in[1];
  const float* in_b      = (const float*)d_in[2];
  const float* in_proj_w = (const float*)d_in[3];
  const float* conv_w    = (const float*)d_in[4];
  const float* conv_b    = (const float*)d_in[5];
  const float* xproj_w   = (const float*)d_in[6];
  const float* dtproj_w  = (const float*)d_in[7];
  const float* dtproj_b  = (const float*)d_in[8];
  const float* A_log     = (const float*)d_in[9];
  const float* D_ssm     = (const float*)d_in[10];
  const float* outproj_w = (const float*)d_in[11];
  const float* norm_w    = (const float*)d_in[12];
  const float* normf_w   = (const float*)d_in[13];
  const float* out_w     = (const float*)d_in[14];
  const float* out_b     = (const float*)d_in[15];
  float* out = (float*)d_out;
  float* ws  = (float*)d_ws;

  // fp32 buffers
  float* h     = ws;                              // TOK*DMODEL
  float* xz    = h + (size_t)TOK * DMODEL;        // TOK*TWOE
  float* u     = xz + (size_t)TOK * TWOE;         // TOK*EDIM
  float* xdb   = u + (size_t)TOK * EDIM;          // TOK*RN2
  float* dl    = xdb + (size_t)TOK * RN2;         // TOK*EDIM
  float* part  = dl + (size_t)TOK * EDIM;         // XSPLIT*TOK*RN2
  float* hend  = part + (size_t)XSPLIT * TOK * RN2;   // BATCH*CH*EDIM*NSTATE
  float* aprod = hend + (size_t)BATCH * CH * EDIM * NSTATE;
  float* hin   = aprod + (size_t)BATCH * CH * EDIM * NSTATE;
  // bf16 buffers
  unsigned short* xn_bf = (unsigned short*)(hin + (size_t)BATCH * CH * EDIM * NSTATE);
  unsigned short* y_bf  = xn_bf + (size_t)TOK * DMODEL;
  unsigned short* u_bf  = y_bf + (size_t)TOK * EDIM;
  unsigned short* w_in  = u_bf + (size_t)TOK * EDIM;     // TWOE*DMODEL
  unsigned short* w_out = w_in + (size_t)TWOE * DMODEL;  // DMODEL*EDIM
  unsigned short* w_x   = w_out + (size_t)DMODEL * EDIM; // 128*EDIM (80 filled)

  dim3 blk(256);

  gemm_tn<EPI_BIAS><<<dim3(DMODEL / 64, TOK / 64), blk, 0, stream>>>(
      x, 32, in_w, 32, in_b, h, DMODEL, TOK, DMODEL, 32);

  for (int l = 0; l < 4; ++l) {
    rmsnorm_k<<<TOK, 256, 0, stream>>>(h, norm_w + l * DMODEL, xn_bf, DMODEL);

    cast_bf16_k<<<(TWOE * DMODEL / 4 + 255) / 256, 256, 0, stream>>>(
        in_proj_w + (size_t)l * TWOE * DMODEL, w_in, TWOE * DMODEL);

    gemm_mfma<128, 128, EPI_STORE, false><<<dim3(TWOE / 128, TOK / 128, 1), blk, 0, stream>>>(
        xn_bf, w_in, xz, TWOE, DMODEL, DMODEL, TWOE, 0);

    conv_silu_k<<<(TOK * EDIM) / 256, 256, 0, stream>>>(
        xz, conv_w + l * EDIM * CONVK, conv_b + l * EDIM, u, u_bf);

    cast_bf16_k<<<(RN2 * EDIM / 4 + 255) / 256, 256, 0, stream>>>(
        xproj_w + (size_t)l * RN2 * EDIM, w_x, RN2 * EDIM);
    gemm_mfma<64, 64, EPI_STORE, true><<<dim3(2, TOK / 64, XSPLIT), blk, 0, stream>>>(
        u_bf, w_x, part, RN2, EDIM / XSPLIT, EDIM, RN2, (size_t)TOK * RN2);
    reduce_part_k<<<(TOK * RN2 / 4 + 255) / 256, 256, 0, stream>>>(part, xdb);

    gemm_tn<EPI_BIAS_SOFTPLUS><<<dim3(EDIM / 64, TOK / 64), blk, 0, stream>>>(
        xdb, RN2, dtproj_w + (size_t)l * EDIM * RDIM, RDIM, dtproj_b + l * EDIM,
        dl, EDIM, TOK, EDIM, RDIM);

    // chunked scan: pass1 -> combine -> pass2
    scan_p1<<<BATCH * (EDIM / 16) * CH, 256, 0, stream>>>(
        dl, u, xdb, A_log + (size_t)l * EDIM * NSTATE, hend, aprod);
    scan_comb<<<(BATCH * EDIM * NSTATE + 255) / 256, 256, 0, stream>>>(
        hend, aprod, hin);
    scan_p2<<<BATCH * (EDIM / 16) * CH, 256, 0, stream>>>(
        dl, u, xdb, xz, A_log + (size_t)l * EDIM * NSTATE, D_ssm + l * EDIM,
        hin, y_bf);

    cast_bf16_k<<<(DMODEL * EDIM / 4 + 255) / 256, 256, 0, stream>>>(
        outproj_w + (size_t)l * DMODEL * EDIM, w_out, DMODEL * EDIM);

    gemm_mfma<64, 64, EPI_ADD, false><<<dim3(DMODEL / 64, TOK / 64, 1), blk, 0, stream>>>(
        y_bf, w_out, h, DMODEL, EDIM, EDIM, DMODEL, 0);
  }

  final_k<<<BATCH, 256, 0, stream>>>(h, normf_w, out_w, out_b, out);
}

// Round 6
// 810.388 us; speedup vs baseline: 3.8691x; 1.0470x over previous
//
#include <hip/hip_runtime.h>
#include <hip/hip_bf16.h>
#include <cmath>

#define BATCH 4
#define SEQ 512
#define TOK (BATCH*SEQ)       // 2048
#define DMODEL 768
#define EDIM 1536
#define TWOE 3072
#define RDIM 48
#define NSTATE 16
#define RN2 80
#define CONVK 4
#define XSPLIT 6              // split-K factor for xproj
#define CH 8                  // scan chunks
#define CL (SEQ/CH)           // 64 steps per chunk

#define EPI_STORE 0
#define EPI_BIAS 1
#define EPI_BIAS_SOFTPLUS 2
#define EPI_ADD 3

typedef short bf16x8 __attribute__((ext_vector_type(8)));
typedef float f32x4 __attribute__((ext_vector_type(4)));

__device__ __forceinline__ unsigned short f2bf(float f) {
  unsigned int u = __builtin_bit_cast(unsigned int, f);
  u = (u + 0x7FFFu + ((u >> 16) & 1u)) >> 16;
  return (unsigned short)u;
}

// ---------------- bf16 MFMA GEMM ----------------
// C[m,n] = sum_k A[m,k]*W[n,k]; A [M,ldk] bf16, W [N,ldk] bf16 row-major.
template<int BM, int BN, int EPI, bool NB>
__global__ __launch_bounds__(256) void gemm_mfma(
    const unsigned short* __restrict__ Abf,
    const unsigned short* __restrict__ Wbf,
    float* __restrict__ C, int ldc, int Kk, int ldk,
    int Nvalid, size_t zCstride, const float* __restrict__ bias) {
  constexpr int WM = BM / 2, WN = BN / 2;
  constexpr int IT = WM / 16, JT = WN / 16;
  __shared__ __align__(16) char smem[(BM + BN) * 128];
  char* ldsA = smem;
  char* ldsB = smem + BM * 128;

  const int tid = threadIdx.x;
  const int wid = tid >> 6, lane = tid & 63;
  const int m0 = blockIdx.y * BM, n0 = blockIdx.x * BN;
  const int wm = (wid >> 1) * WM, wn = (wid & 1) * WN;
  const int quad = lane >> 4, l15 = lane & 15;

  const int srow = lane >> 3;
  const int kc = (lane & 7) ^ srow;
  const int koff = blockIdx.z * Kk;
  C += (size_t)blockIdx.z * zCstride;
  const unsigned short* gA = Abf + (size_t)(m0 + srow) * ldk + kc * 8 + koff;
  const unsigned short* gB = Wbf + (size_t)(n0 + srow) * ldk + kc * 8 + koff;

  f32x4 acc[IT][JT] = {};

  for (int k0 = 0; k0 < Kk; k0 += 64) {
#pragma unroll
    for (int c = wid; c < BM / 8; c += 4)
      __builtin_amdgcn_global_load_lds(
          (const __attribute__((address_space(1))) void*)(gA + (size_t)(c * 8) * ldk + k0),
          (__attribute__((address_space(3))) void*)(ldsA + c * 1024), 16, 0, 0);
#pragma unroll
    for (int c = wid; c < BN / 8; c += 4)
      __builtin_amdgcn_global_load_lds(
          (const __attribute__((address_space(1))) void*)(gB + (size_t)(c * 8) * ldk + k0),
          (__attribute__((address_space(3))) void*)(ldsB + c * 1024), 16, 0, 0);
    asm volatile("s_waitcnt vmcnt(0)" ::: "memory");
    __syncthreads();
#pragma unroll
    for (int t = 0; t < 2; ++t) {
      const int cc = t * 4 + quad;
      bf16x8 av[IT], bv[JT];
#pragma unroll
      for (int i = 0; i < IT; ++i) {
        const int row = wm + i * 16 + l15;
        const int slot = cc ^ (row & 7);
        av[i] = *(const bf16x8*)(ldsA + row * 128 + slot * 16);
      }
#pragma unroll
      for (int j = 0; j < JT; ++j) {
        const int row = wn + j * 16 + l15;
        const int slot = cc ^ (row & 7);
        bv[j] = *(const bf16x8*)(ldsB + row * 128 + slot * 16);
      }
#pragma unroll
      for (int i = 0; i < IT; ++i)
#pragma unroll
        for (int j = 0; j < JT; ++j)
          acc[i][j] = __builtin_amdgcn_mfma_f32_16x16x32_bf16(av[i], bv[j], acc[i][j], 0, 0, 0);
    }
    __syncthreads();
  }

#pragma unroll
  for (int i = 0; i < IT; ++i) {
#pragma unroll
    for (int r = 0; r < 4; ++r) {
      const int m = m0 + wm + i * 16 + quad * 4 + r;
      float* crow = C + (size_t)m * ldc + n0 + wn;
#pragma unroll
      for (int j = 0; j < JT; ++j) {
        const int n = j * 16 + l15;
        if (NB && (n0 + wn + n) >= Nvalid) continue;
        float v = acc[i][j][r];
        if (EPI == EPI_BIAS_SOFTPLUS) {
          v += bias[n0 + wn + n];
          v = (v > 20.f) ? v : log1pf(expf(v));
        }
        if (EPI == EPI_ADD) v += crow[n];
        crow[n] = v;
      }
    }
  }
}

// Sum XSPLIT partials into xdb; also emit zero-padded bf16 dt [TOK][64].
__global__ __launch_bounds__(256) void reduce_part_k(
    const float* __restrict__ part, float* __restrict__ out,
    unsigned short* __restrict__ dtbf) {
  int i = (blockIdx.x * 256 + threadIdx.x) * 4;
  if (i >= TOK * RN2) return;
  float4 s = *(const float4*)(part + i);
#pragma unroll
  for (int z = 1; z < XSPLIT; ++z) {
    float4 v = *(const float4*)(part + (size_t)z * TOK * RN2 + i);
    s.x += v.x; s.y += v.y; s.z += v.z; s.w += v.w;
  }
  *(float4*)(out + i) = s;
  int row = i / RN2, col = i % RN2;
  if (col < RDIM) {
    ushort4 r;
    r.x = f2bf(s.x); r.y = f2bf(s.y); r.z = f2bf(s.z); r.w = f2bf(s.w);
    *(ushort4*)(dtbf + (size_t)row * 64 + col) = r;
  }
  if (col < 16) {   // zero-fill pad cols 48..63
    ushort4 z0 = {0, 0, 0, 0};
    *(ushort4*)(dtbf + (size_t)row * 64 + RDIM + col) = z0;
  }
}

// dtproj_w [EDIM][48] -> padded bf16 [EDIM][64]
__global__ __launch_bounds__(256) void cast_dtw_k(
    const float* __restrict__ w, unsigned short* __restrict__ o) {
  int i = (blockIdx.x * 256 + threadIdx.x) * 4;
  if (i >= EDIM * 64) return;
  int row = i / 64, col = i % 64;
  ushort4 r = {0, 0, 0, 0};
  if (col < RDIM) {
    float4 v = *(const float4*)(w + (size_t)row * RDIM + col);
    r.x = f2bf(v.x); r.y = f2bf(v.y); r.z = f2bf(v.z); r.w = f2bf(v.w);
  }
  *(ushort4*)(o + i) = r;
}

// ---------------- fp32 tiled GEMM (initial proj only) ----------------
template<int EPI>
__global__ __launch_bounds__(256) void gemm_tn(
    const float* __restrict__ A, int lda,
    const float* __restrict__ W, int ldw,
    const float* __restrict__ bias,
    float* __restrict__ C, int ldc,
    int M, int Nn, int Kk) {
  __shared__ float As[16][68];
  __shared__ float Bs[16][68];
  const int tid = threadIdx.x;
  const int m0 = blockIdx.y * 64, n0 = blockIdx.x * 64;
  const int lr = tid >> 2;
  const int lc = (tid & 3) << 2;
  const int ty = tid >> 4, tx = tid & 15;
  float acc[4][4] = {};

  for (int k0 = 0; k0 < Kk; k0 += 16) {
    {
      int m = m0 + lr;
      float4 v = make_float4(0.f, 0.f, 0.f, 0.f);
      if (m < M) v = *(const float4*)(A + (size_t)m * lda + k0 + lc);
      As[lc + 0][lr] = v.x; As[lc + 1][lr] = v.y;
      As[lc + 2][lr] = v.z; As[lc + 3][lr] = v.w;
    }
    {
      int nn = n0 + lr;
      float4 v = make_float4(0.f, 0.f, 0.f, 0.f);
      if (nn < Nn) v = *(const float4*)(W + (size_t)nn * ldw + k0 + lc);
      Bs[lc + 0][lr] = v.x; Bs[lc + 1][lr] = v.y;
      Bs[lc + 2][lr] = v.z; Bs[lc + 3][lr] = v.w;
    }
    __syncthreads();
#pragma unroll
    for (int kk = 0; kk < 16; ++kk) {
      float av[4], bv[4];
#pragma unroll
      for (int i = 0; i < 4; ++i) av[i] = As[kk][ty * 4 + i];
#pragma unroll
      for (int j = 0; j < 4; ++j) bv[j] = Bs[kk][tx * 4 + j];
#pragma unroll
      for (int i = 0; i < 4; ++i)
#pragma unroll
        for (int j = 0; j < 4; ++j)
          acc[i][j] += av[i] * bv[j];
    }
    __syncthreads();
  }

#pragma unroll
  for (int i = 0; i < 4; ++i) {
    int m = m0 + ty * 4 + i;
    if (m >= M) continue;
#pragma unroll
    for (int j = 0; j < 4; ++j) {
      int nn = n0 + tx * 4 + j;
      if (nn >= Nn) continue;
      float v = acc[i][j];
      float* cp = C + (size_t)m * ldc + nn;
      if (EPI == EPI_BIAS) v += bias[nn];
      if (EPI == EPI_ADD) v += *cp;
      *cp = v;
    }
  }
}

__global__ __launch_bounds__(256) void cast_bf16_k(
    const float* __restrict__ w, unsigned short* __restrict__ o, int n) {
  int i = (blockIdx.x * 256 + threadIdx.x) * 4;
  if (i >= n) return;
  float4 v = *(const float4*)(w + i);
  ushort4 r;
  r.x = f2bf(v.x); r.y = f2bf(v.y); r.z = f2bf(v.z); r.w = f2bf(v.w);
  *(ushort4*)(o + i) = r;
}

__global__ __launch_bounds__(256) void rmsnorm_k(
    const float* __restrict__ x, const float* __restrict__ w,
    unsigned short* __restrict__ o, int D) {
  const int t = blockIdx.x;
  const float* row = x + (size_t)t * D;
  __shared__ float ls[8];
  const int lane = threadIdx.x & 63, wave = threadIdx.x >> 6;
  float s = 0.f;
  for (int i = threadIdx.x; i < D; i += 256) { float v = row[i]; s += v * v; }
  for (int off = 32; off; off >>= 1) s += __shfl_down(s, off);
  if (lane == 0) ls[wave] = s;
  __syncthreads();
  float tot = ls[0] + ls[1] + ls[2] + ls[3];
  float rs = rsqrtf(tot / (float)D + 1e-5f);
  for (int i = threadIdx.x; i < D; i += 256)
    o[(size_t)t * D + i] = f2bf(row[i] * rs * w[i]);
}

// Depthwise causal conv + bias + silu, 4 e/thread.
__global__ __launch_bounds__(256) void conv_silu4_k(
    const float* __restrict__ xz, const float* __restrict__ cw,
    const float* __restrict__ cb, float* __restrict__ u,
    unsigned short* __restrict__ ubf) {
  const int idx = blockIdx.x * 256 + threadIdx.x;     // TOK*EDIM/4
  const int ec = (idx % (EDIM / 4)) * 4;
  const int tok = idx / (EDIM / 4);
  const int tl = tok & (SEQ - 1);
  float4 acc = *(const float4*)(cb + ec);
  float wt[16];
  *(float4*)(wt + 0)  = *(const float4*)(cw + ec * 4);
  *(float4*)(wt + 4)  = *(const float4*)(cw + ec * 4 + 4);
  *(float4*)(wt + 8)  = *(const float4*)(cw + ec * 4 + 8);
  *(float4*)(wt + 12) = *(const float4*)(cw + ec * 4 + 12);
#pragma unroll
  for (int j = 0; j < CONVK; ++j) {
    int tt = tl - (CONVK - 1) + j;
    if (tt >= 0) {
      float4 xv = *(const float4*)(xz + (size_t)(tok - (CONVK - 1) + j) * TWOE + ec);
      acc.x += xv.x * wt[0 * 4 + j];
      acc.y += xv.y * wt[1 * 4 + j];
      acc.z += xv.z * wt[2 * 4 + j];
      acc.w += xv.w * wt[3 * 4 + j];
    }
  }
  float4 s;
  s.x = acc.x / (1.f + __expf(-acc.x));
  s.y = acc.y / (1.f + __expf(-acc.y));
  s.z = acc.z / (1.f + __expf(-acc.z));
  s.w = acc.w / (1.f + __expf(-acc.w));
  *(float4*)(u + (size_t)idx * 4) = s;
  ushort4 r;
  r.x = f2bf(s.x); r.y = f2bf(s.y); r.z = f2bf(s.z); r.w = f2bf(s.w);
  *(ushort4*)(ubf + (size_t)idx * 4) = r;
}

// ---------------- chunked selective scan ----------------
// Pass 1: local scan with h_in=0; outputs hend, aprod=exp(A*sum dv).
__global__ __launch_bounds__(256) void scan_p1(
    const float* __restrict__ delta, const float* __restrict__ u,
    const float* __restrict__ xdbl, const float* __restrict__ A_log,
    float* __restrict__ hend, float* __restrict__ aprod) {
  const int tid = threadIdx.x;
  const int g = tid >> 4, n = tid & 15;
  const int nch = blockIdx.x & (CH - 1);
  const int rem = blockIdx.x >> 3;
  const int e0 = (rem % (EDIM / 16)) * 16;
  const int b = rem / (EDIM / 16);
  const int e = e0 + g;
  const float A = -__expf(A_log[e * NSTATE + n]);
  const size_t base = (size_t)b * SEQ + nch * CL;

  __shared__ float s_dv[2][8][16];
  __shared__ float s_uv[2][8][16];
  __shared__ float s_B[2][8][16];

  const int role = tid >> 5;
  const int rt = (tid & 31) >> 2;
  const int rq = (tid & 3) * 4;
  const float* gp = nullptr; size_t stp = 0; float* ld0 = nullptr;
  if (role == 0) { gp = delta + (base + rt) * EDIM + e0 + rq; stp = 8 * (size_t)EDIM; ld0 = &s_dv[0][rt][rq]; }
  else if (role == 1) { gp = u + (base + rt) * EDIM + e0 + rq; stp = 8 * (size_t)EDIM; ld0 = &s_uv[0][rt][rq]; }
  else if (role == 2) { gp = xdbl + (base + rt) * RN2 + RDIM + rq; stp = 8 * (size_t)RN2; ld0 = &s_B[0][rt][rq]; }
  if (role < 3) { float4 v = *(const float4*)gp; gp += stp; *(float4*)ld0 = v; }

  float h = 0.f, sdv = 0.f;
  for (int it = 0; it < CL / 8; ++it) {
    const int cur = it & 1;
    const bool hn = (it < CL / 8 - 1) && (role < 3);
    float4 nv;
    if (hn) { nv = *(const float4*)gp; gp += stp; }
    __syncthreads();
#pragma unroll
    for (int j = 0; j < 8; ++j) {
      float dv = s_dv[cur][j][g];
      float uv = s_uv[cur][j][g];
      float Bv = s_B[cur][j][n];
      h = __expf(dv * A) * h + (dv * uv) * Bv;
      sdv += dv;
    }
    if (hn) *(float4*)(ld0 + (cur ^ 1) * 128) = nv;
  }
  size_t o = (((size_t)b * CH + nch) * EDIM + e) * NSTATE + n;
  hend[o] = h;
  aprod[o] = __expf(A * sdv);
}

// Combine: prefix over chunks -> h_in per chunk.
__global__ __launch_bounds__(256) void scan_comb(
    const float* __restrict__ hend, const float* __restrict__ aprod,
    float* __restrict__ hin) {
  int i = blockIdx.x * 256 + threadIdx.x;
  if (i >= BATCH * EDIM * NSTATE) return;
  int b = i / (EDIM * NSTATE);
  int en = i % (EDIM * NSTATE);
  float he[CH], ap[CH];
#pragma unroll
  for (int c = 0; c < CH; ++c) {
    size_t o = ((size_t)(b * CH + c)) * EDIM * NSTATE + en;
    he[c] = hend[o]; ap[c] = aprod[o];
  }
  float hv = 0.f;
#pragma unroll
  for (int c = 0; c < CH; ++c) {
    size_t o = ((size_t)(b * CH + c)) * EDIM * NSTATE + en;
    hin[o] = hv;
    hv = he[c] + ap[c] * hv;
  }
}

// Pass 2: scan seeded with h_in; deferred epilogue every 8 steps.
__global__ __launch_bounds__(256) void scan_p2(
    const float* __restrict__ delta, const float* __restrict__ u,
    const float* __restrict__ xdbl, const float* __restrict__ xz,
    const float* __restrict__ A_log, const float* __restrict__ D_ssm,
    const float* __restrict__ hin, unsigned short* __restrict__ y) {
  const int tid = threadIdx.x;
  const int g = tid >> 4, n = tid & 15;
  const int nch = blockIdx.x & (CH - 1);
  const int rem = blockIdx.x >> 3;
  const int e0 = (rem % (EDIM / 16)) * 16;
  const int b = rem / (EDIM / 16);
  const int e = e0 + g;
  const float A = -__expf(A_log[e * NSTATE + n]);
  const float Dv = D_ssm[e];
  const size_t base = (size_t)b * SEQ + nch * CL;

  __shared__ float s_dv[2][8][16];
  __shared__ float s_uv[2][8][16];
  __shared__ float s_rs[2][8][16];
  __shared__ float s_B[2][8][16];
  __shared__ float s_C[2][8][16];

  const int role = tid >> 5;
  const int rt = (tid & 31) >> 2;
  const int rq = (tid & 3) * 4;
  const float* gp = nullptr; size_t stp = 0; float* ld0 = nullptr;
  if (role == 0) { gp = delta + (base + rt) * EDIM + e0 + rq; stp = 8 * (size_t)EDIM; ld0 = &s_dv[0][rt][rq]; }
  else if (role == 1) { gp = u + (base + rt) * EDIM + e0 + rq; stp = 8 * (size_t)EDIM; ld0 = &s_uv[0][rt][rq]; }
  else if (role == 2) { gp = xz + (base + rt) * TWOE + EDIM + e0 + rq; stp = 8 * (size_t)TWOE; ld0 = &s_rs[0][rt][rq]; }
  else if (role == 3) { gp = xdbl + (base + rt) * RN2 + RDIM + rq; stp = 8 * (size_t)RN2; ld0 = &s_B[0][rt][rq]; }
  else if (role == 4) { gp = xdbl + (base + rt) * RN2 + RDIM + NSTATE + rq; stp = 8 * (size_t)RN2; ld0 = &s_C[0][rt][rq]; }
  if (role < 5) { float4 v = *(const float4*)gp; gp += stp; *(float4*)ld0 = v; }

  float hstate = hin[(((size_t)b * CH + nch) * EDIM + e) * NSTATE + n];
  float pv = 0.f;
  unsigned short* yp = y + base * EDIM + e;
  for (int it = 0; it < CL / 8; ++it) {
    const int cur = it & 1;
    const bool hn = (it < CL / 8 - 1) && (role < 5);
    float4 nv;
    if (hn) { nv = *(const float4*)gp; gp += stp; }
    __syncthreads();
#pragma unroll
    for (int j = 0; j < 8; ++j) {
      float dv = s_dv[cur][j][g];
      float uv = s_uv[cur][j][g];
      float Bv = s_B[cur][j][n];
      float Cv = s_C[cur][j][n];
      hstate = __expf(dv * A) * hstate + (dv * uv) * Bv;
      float p = hstate * Cv;
      p += __shfl_xor(p, 1); p += __shfl_xor(p, 2);
      p += __shfl_xor(p, 4); p += __shfl_xor(p, 8);
      pv = (n == j) ? p : pv;      // save my step's sum
    }
    // deferred epilogue: lanes 0..7 emit this batch's 8 outputs
    if (n < 8) {
      float uvv = s_uv[cur][n][g];
      float rsv = s_rs[cur][n][g];
      float sil = rsv / (1.f + __expf(-rsv));
      yp[(size_t)(it * 8 + n) * EDIM] = f2bf((pv + uvv * Dv) * sil);
    }
    if (hn) *(float4*)(ld0 + (cur ^ 1) * 128) = nv;
  }
}

// Final: rmsnorm(last token) -> dot out_w -> sigmoid
__global__ __launch_bounds__(256) void final_k(
    const float* __restrict__ h, const float* __restrict__ nw,
    const float* __restrict__ ow, const float* __restrict__ ob,
    float* __restrict__ out) {
  const int b = blockIdx.x;
  const float* row = h + ((size_t)(b * SEQ + SEQ - 1)) * DMODEL;
  __shared__ float ls[8];
  __shared__ float ls2[8];
  const int lane = threadIdx.x & 63, wave = threadIdx.x >> 6;
  float s = 0.f;
  for (int i = threadIdx.x; i < DMODEL; i += 256) { float v = row[i]; s += v * v; }
  for (int off = 32; off; off >>= 1) s += __shfl_down(s, off);
  if (lane == 0) ls[wave] = s;
  __syncthreads();
  float tot = ls[0] + ls[1] + ls[2] + ls[3];
  float rs = rsqrtf(tot / (float)DMODEL + 1e-5f);
  float d = 0.f;
  for (int i = threadIdx.x; i < DMODEL; i += 256)
    d += row[i] * rs * nw[i] * ow[i];
  for (int off = 32; off; off >>= 1) d += __shfl_down(d, off);
  if (lane == 0) ls2[wave] = d;
  __syncthreads();
  if (threadIdx.x == 0) {
    float dot = ls2[0] + ls2[1] + ls2[2] + ls2[3] + ob[0];
    out[b] = 1.f / (1.f + expf(-dot));
  }
}

extern "C" void kernel_launch(void* const* d_in, const int* in_sizes, int n_in,
                              void* d_out, int out_size, void* d_ws, size_t ws_size,
                              hipStream_t stream) {
  const float* x         = (const float*)d_in[0];
  const float* in_w      = (const float*)d_in[1];
  const float* in_b      = (const float*)d_in[2];
  const float* in_proj_w = (const float*)d_in[3];
  const float* conv_w    = (const float*)d_in[4];
  const float* conv_b    = (const float*)d_in[5];
  const float* xproj_w   = (const float*)d_in[6];
  const float* dtproj_w  = (const float*)d_in[7];
  const float* dtproj_b  = (const float*)d_in[8];
  const float* A_log     = (const float*)d_in[9];
  const float* D_ssm     = (const float*)d_in[10];
  const float* outproj_w = (const float*)d_in[11];
  const float* norm_w    = (const float*)d_in[12];
  const float* normf_w   = (const float*)d_in[13];
  const float* out_w     = (const float*)d_in[14];
  const float* out_b     = (const float*)d_in[15];
  float* out = (float*)d_out;
  float* ws  = (float*)d_ws;

  // fp32 buffers
  float* h     = ws;                              // TOK*DMODEL
  float* xz    = h + (size_t)TOK * DMODEL;        // TOK*TWOE
  float* u     = xz + (size_t)TOK * TWOE;         // TOK*EDIM
  float* xdb   = u + (size_t)TOK * EDIM;          // TOK*RN2
  float* dl    = xdb + (size_t)TOK * RN2;         // TOK*EDIM
  float* part  = dl + (size_t)TOK * EDIM;         // XSPLIT*TOK*RN2
  float* hend  = part + (size_t)XSPLIT * TOK * RN2;
  float* aprod = hend + (size_t)BATCH * CH * EDIM * NSTATE;
  float* hin   = aprod + (size_t)BATCH * CH * EDIM * NSTATE;
  // bf16 buffers
  unsigned short* xn_bf = (unsigned short*)(hin + (size_t)BATCH * CH * EDIM * NSTATE);
  unsigned short* y_bf  = xn_bf + (size_t)TOK * DMODEL;
  unsigned short* u_bf  = y_bf + (size_t)TOK * EDIM;
  unsigned short* w_in  = u_bf + (size_t)TOK * EDIM;     // TWOE*DMODEL
  unsigned short* w_out = w_in + (size_t)TWOE * DMODEL;  // DMODEL*EDIM
  unsigned short* w_x   = w_out + (size_t)DMODEL * EDIM; // 128*EDIM (80 filled)
  unsigned short* dt_bf = w_x + (size_t)128 * EDIM;      // TOK*64
  unsigned short* w_dt  = dt_bf + (size_t)TOK * 64;      // EDIM*64

  dim3 blk(256);

  gemm_tn<EPI_BIAS><<<dim3(DMODEL / 64, TOK / 64), blk, 0, stream>>>(
      x, 32, in_w, 32, in_b, h, DMODEL, TOK, DMODEL, 32);

  for (int l = 0; l < 4; ++l) {
    rmsnorm_k<<<TOK, 256, 0, stream>>>(h, norm_w + l * DMODEL, xn_bf, DMODEL);

    cast_bf16_k<<<(TWOE * DMODEL / 4 + 255) / 256, 256, 0, stream>>>(
        in_proj_w + (size_t)l * TWOE * DMODEL, w_in, TWOE * DMODEL);

    gemm_mfma<128, 128, EPI_STORE, false><<<dim3(TWOE / 128, TOK / 128, 1), blk, 0, stream>>>(
        xn_bf, w_in, xz, TWOE, DMODEL, DMODEL, TWOE, 0, nullptr);

    conv_silu4_k<<<(TOK * EDIM / 4) / 256, 256, 0, stream>>>(
        xz, conv_w + l * EDIM * CONVK, conv_b + l * EDIM, u, u_bf);

    cast_bf16_k<<<(RN2 * EDIM / 4 + 255) / 256, 256, 0, stream>>>(
        xproj_w + (size_t)l * RN2 * EDIM, w_x, RN2 * EDIM);
    gemm_mfma<64, 64, EPI_STORE, true><<<dim3(2, TOK / 64, XSPLIT), blk, 0, stream>>>(
        u_bf, w_x, part, RN2, EDIM / XSPLIT, EDIM, RN2, (size_t)TOK * RN2, nullptr);
    reduce_part_k<<<(TOK * RN2 / 4 + 255) / 256, 256, 0, stream>>>(part, xdb, dt_bf);

    // delta = softplus(dt @ dtproj_w.T + b)  (MFMA, K=64 padded)
    cast_dtw_k<<<(EDIM * 64 / 4 + 255) / 256, 256, 0, stream>>>(
        dtproj_w + (size_t)l * EDIM * RDIM, w_dt);
    gemm_mfma<64, 64, EPI_BIAS_SOFTPLUS, false><<<dim3(EDIM / 64, TOK / 64, 1), blk, 0, stream>>>(
        dt_bf, w_dt, dl, EDIM, 64, 64, EDIM, 0, dtproj_b + l * EDIM);

    scan_p1<<<BATCH * (EDIM / 16) * CH, 256, 0, stream>>>(
        dl, u, xdb, A_log + (size_t)l * EDIM * NSTATE, hend, aprod);
    scan_comb<<<(BATCH * EDIM * NSTATE + 255) / 256, 256, 0, stream>>>(
        hend, aprod, hin);
    scan_p2<<<BATCH * (EDIM / 16) * CH, 256, 0, stream>>>(
        dl, u, xdb, xz, A_log + (size_t)l * EDIM * NSTATE, D_ssm + l * EDIM,
        hin, y_bf);

    cast_bf16_k<<<(DMODEL * EDIM / 4 + 255) / 256, 256, 0, stream>>>(
        outproj_w + (size_t)l * DMODEL * EDIM, w_out, DMODEL * EDIM);

    gemm_mfma<64, 64, EPI_ADD, false><<<dim3(DMODEL / 64, TOK / 64, 1), blk, 0, stream>>>(
        y_bf, w_out, h, DMODEL, EDIM, EDIM, DMODEL, 0, nullptr);
  }

  final_k<<<BATCH, 256, 0, stream>>>(h, normf_w, out_w, out_b, out);
}

// Round 7
// 632.501 us; speedup vs baseline: 4.9573x; 1.2812x over previous
//
#include <hip/hip_runtime.h>
#include <hip/hip_bf16.h>
#include <cmath>

#define BATCH 4
#define SEQ 512
#define TOK (BATCH*SEQ)       // 2048
#define DMODEL 768
#define EDIM 1536
#define TWOE 3072
#define RDIM 48
#define NSTATE 16
#define RN2 80
#define CONVK 4
#define XSPLIT 6              // split-K factor for xproj
#define CH 8                  // scan chunks
#define CL (SEQ/CH)           // 64 steps per chunk
#define EBLK 64               // e's per scan block

#define EPI_STORE 0
#define EPI_BIAS 1
#define EPI_BIAS_SOFTPLUS 2
#define EPI_ADD 3

typedef short bf16x8 __attribute__((ext_vector_type(8)));
typedef float f32x4 __attribute__((ext_vector_type(4)));

__device__ __forceinline__ unsigned short f2bf(float f) {
  unsigned int u = __builtin_bit_cast(unsigned int, f);
  u = (u + 0x7FFFu + ((u >> 16) & 1u)) >> 16;
  return (unsigned short)u;
}

// ---------------- bf16 MFMA GEMM ----------------
template<int BM, int BN, int EPI, bool NB>
__global__ __launch_bounds__(256) void gemm_mfma(
    const unsigned short* __restrict__ Abf,
    const unsigned short* __restrict__ Wbf,
    float* __restrict__ C, int ldc, int Kk, int ldk,
    int Nvalid, size_t zCstride, const float* __restrict__ bias) {
  constexpr int WM = BM / 2, WN = BN / 2;
  constexpr int IT = WM / 16, JT = WN / 16;
  __shared__ __align__(16) char smem[(BM + BN) * 128];
  char* ldsA = smem;
  char* ldsB = smem + BM * 128;

  const int tid = threadIdx.x;
  const int wid = tid >> 6, lane = tid & 63;
  const int m0 = blockIdx.y * BM, n0 = blockIdx.x * BN;
  const int wm = (wid >> 1) * WM, wn = (wid & 1) * WN;
  const int quad = lane >> 4, l15 = lane & 15;

  const int srow = lane >> 3;
  const int kc = (lane & 7) ^ srow;
  const int koff = blockIdx.z * Kk;
  C += (size_t)blockIdx.z * zCstride;
  const unsigned short* gA = Abf + (size_t)(m0 + srow) * ldk + kc * 8 + koff;
  const unsigned short* gB = Wbf + (size_t)(n0 + srow) * ldk + kc * 8 + koff;

  f32x4 acc[IT][JT] = {};

  for (int k0 = 0; k0 < Kk; k0 += 64) {
#pragma unroll
    for (int c = wid; c < BM / 8; c += 4)
      __builtin_amdgcn_global_load_lds(
          (const __attribute__((address_space(1))) void*)(gA + (size_t)(c * 8) * ldk + k0),
          (__attribute__((address_space(3))) void*)(ldsA + c * 1024), 16, 0, 0);
#pragma unroll
    for (int c = wid; c < BN / 8; c += 4)
      __builtin_amdgcn_global_load_lds(
          (const __attribute__((address_space(1))) void*)(gB + (size_t)(c * 8) * ldk + k0),
          (__attribute__((address_space(3))) void*)(ldsB + c * 1024), 16, 0, 0);
    asm volatile("s_waitcnt vmcnt(0)" ::: "memory");
    __syncthreads();
#pragma unroll
    for (int t = 0; t < 2; ++t) {
      const int cc = t * 4 + quad;
      bf16x8 av[IT], bv[JT];
#pragma unroll
      for (int i = 0; i < IT; ++i) {
        const int row = wm + i * 16 + l15;
        const int slot = cc ^ (row & 7);
        av[i] = *(const bf16x8*)(ldsA + row * 128 + slot * 16);
      }
#pragma unroll
      for (int j = 0; j < JT; ++j) {
        const int row = wn + j * 16 + l15;
        const int slot = cc ^ (row & 7);
        bv[j] = *(const bf16x8*)(ldsB + row * 128 + slot * 16);
      }
#pragma unroll
      for (int i = 0; i < IT; ++i)
#pragma unroll
        for (int j = 0; j < JT; ++j)
          acc[i][j] = __builtin_amdgcn_mfma_f32_16x16x32_bf16(av[i], bv[j], acc[i][j], 0, 0, 0);
    }
    __syncthreads();
  }

#pragma unroll
  for (int i = 0; i < IT; ++i) {
#pragma unroll
    for (int r = 0; r < 4; ++r) {
      const int m = m0 + wm + i * 16 + quad * 4 + r;
      float* crow = C + (size_t)m * ldc + n0 + wn;
#pragma unroll
      for (int j = 0; j < JT; ++j) {
        const int n = j * 16 + l15;
        if (NB && (n0 + wn + n) >= Nvalid) continue;
        float v = acc[i][j][r];
        if (EPI == EPI_BIAS_SOFTPLUS) {
          v += bias[n0 + wn + n];
          v = (v > 20.f) ? v : log1pf(expf(v));
        }
        if (EPI == EPI_ADD) v += crow[n];
        crow[n] = v;
      }
    }
  }
}

// Sum XSPLIT partials into xdb; also emit zero-padded bf16 dt [TOK][64].
__global__ __launch_bounds__(256) void reduce_part_k(
    const float* __restrict__ part, float* __restrict__ out,
    unsigned short* __restrict__ dtbf) {
  int i = (blockIdx.x * 256 + threadIdx.x) * 4;
  if (i >= TOK * RN2) return;
  float4 s = *(const float4*)(part + i);
#pragma unroll
  for (int z = 1; z < XSPLIT; ++z) {
    float4 v = *(const float4*)(part + (size_t)z * TOK * RN2 + i);
    s.x += v.x; s.y += v.y; s.z += v.z; s.w += v.w;
  }
  *(float4*)(out + i) = s;
  int row = i / RN2, col = i % RN2;
  if (col < RDIM) {
    ushort4 r;
    r.x = f2bf(s.x); r.y = f2bf(s.y); r.z = f2bf(s.z); r.w = f2bf(s.w);
    *(ushort4*)(dtbf + (size_t)row * 64 + col) = r;
  }
  if (col < 16) {
    ushort4 z0 = {0, 0, 0, 0};
    *(ushort4*)(dtbf + (size_t)row * 64 + RDIM + col) = z0;
  }
}

// dtproj_w [EDIM][48] -> padded bf16 [EDIM][64]
__global__ __launch_bounds__(256) void cast_dtw_k(
    const float* __restrict__ w, unsigned short* __restrict__ o) {
  int i = (blockIdx.x * 256 + threadIdx.x) * 4;
  if (i >= EDIM * 64) return;
  int row = i / 64, col = i % 64;
  ushort4 r = {0, 0, 0, 0};
  if (col < RDIM) {
    float4 v = *(const float4*)(w + (size_t)row * RDIM + col);
    r.x = f2bf(v.x); r.y = f2bf(v.y); r.z = f2bf(v.z); r.w = f2bf(v.w);
  }
  *(ushort4*)(o + i) = r;
}

// ---------------- fp32 tiled GEMM (initial proj only) ----------------
template<int EPI>
__global__ __launch_bounds__(256) void gemm_tn(
    const float* __restrict__ A, int lda,
    const float* __restrict__ W, int ldw,
    const float* __restrict__ bias,
    float* __restrict__ C, int ldc,
    int M, int Nn, int Kk) {
  __shared__ float As[16][68];
  __shared__ float Bs[16][68];
  const int tid = threadIdx.x;
  const int m0 = blockIdx.y * 64, n0 = blockIdx.x * 64;
  const int lr = tid >> 2;
  const int lc = (tid & 3) << 2;
  const int ty = tid >> 4, tx = tid & 15;
  float acc[4][4] = {};

  for (int k0 = 0; k0 < Kk; k0 += 16) {
    {
      int m = m0 + lr;
      float4 v = make_float4(0.f, 0.f, 0.f, 0.f);
      if (m < M) v = *(const float4*)(A + (size_t)m * lda + k0 + lc);
      As[lc + 0][lr] = v.x; As[lc + 1][lr] = v.y;
      As[lc + 2][lr] = v.z; As[lc + 3][lr] = v.w;
    }
    {
      int nn = n0 + lr;
      float4 v = make_float4(0.f, 0.f, 0.f, 0.f);
      if (nn < Nn) v = *(const float4*)(W + (size_t)nn * ldw + k0 + lc);
      Bs[lc + 0][lr] = v.x; Bs[lc + 1][lr] = v.y;
      Bs[lc + 2][lr] = v.z; Bs[lc + 3][lr] = v.w;
    }
    __syncthreads();
#pragma unroll
    for (int kk = 0; kk < 16; ++kk) {
      float av[4], bv[4];
#pragma unroll
      for (int i = 0; i < 4; ++i) av[i] = As[kk][ty * 4 + i];
#pragma unroll
      for (int j = 0; j < 4; ++j) bv[j] = Bs[kk][tx * 4 + j];
#pragma unroll
      for (int i = 0; i < 4; ++i)
#pragma unroll
        for (int j = 0; j < 4; ++j)
          acc[i][j] += av[i] * bv[j];
    }
    __syncthreads();
  }

#pragma unroll
  for (int i = 0; i < 4; ++i) {
    int m = m0 + ty * 4 + i;
    if (m >= M) continue;
#pragma unroll
    for (int j = 0; j < 4; ++j) {
      int nn = n0 + tx * 4 + j;
      if (nn >= Nn) continue;
      float v = acc[i][j];
      float* cp = C + (size_t)m * ldc + nn;
      if (EPI == EPI_BIAS) v += bias[nn];
      if (EPI == EPI_ADD) v += *cp;
      *cp = v;
    }
  }
}

__global__ __launch_bounds__(256) void cast_bf16_k(
    const float* __restrict__ w, unsigned short* __restrict__ o, int n) {
  int i = (blockIdx.x * 256 + threadIdx.x) * 4;
  if (i >= n) return;
  float4 v = *(const float4*)(w + i);
  ushort4 r;
  r.x = f2bf(v.x); r.y = f2bf(v.y); r.z = f2bf(v.z); r.w = f2bf(v.w);
  *(ushort4*)(o + i) = r;
}

__global__ __launch_bounds__(256) void rmsnorm_k(
    const float* __restrict__ x, const float* __restrict__ w,
    unsigned short* __restrict__ o, int D) {
  const int t = blockIdx.x;
  const float* row = x + (size_t)t * D;
  __shared__ float ls[8];
  const int lane = threadIdx.x & 63, wave = threadIdx.x >> 6;
  float s = 0.f;
  for (int i = threadIdx.x; i < D; i += 256) { float v = row[i]; s += v * v; }
  for (int off = 32; off; off >>= 1) s += __shfl_down(s, off);
  if (lane == 0) ls[wave] = s;
  __syncthreads();
  float tot = ls[0] + ls[1] + ls[2] + ls[3];
  float rs = rsqrtf(tot / (float)D + 1e-5f);
  for (int i = threadIdx.x; i < D; i += 256)
    o[(size_t)t * D + i] = f2bf(row[i] * rs * w[i]);
}

// Depthwise causal conv + bias + silu, 4 e/thread.
__global__ __launch_bounds__(256) void conv_silu4_k(
    const float* __restrict__ xz, const float* __restrict__ cw,
    const float* __restrict__ cb, float* __restrict__ u,
    unsigned short* __restrict__ ubf) {
  const int idx = blockIdx.x * 256 + threadIdx.x;
  const int ec = (idx % (EDIM / 4)) * 4;
  const int tok = idx / (EDIM / 4);
  const int tl = tok & (SEQ - 1);
  float4 acc = *(const float4*)(cb + ec);
  float wt[16];
  *(float4*)(wt + 0)  = *(const float4*)(cw + ec * 4);
  *(float4*)(wt + 4)  = *(const float4*)(cw + ec * 4 + 4);
  *(float4*)(wt + 8)  = *(const float4*)(cw + ec * 4 + 8);
  *(float4*)(wt + 12) = *(const float4*)(cw + ec * 4 + 12);
#pragma unroll
  for (int j = 0; j < CONVK; ++j) {
    int tt = tl - (CONVK - 1) + j;
    if (tt >= 0) {
      float4 xv = *(const float4*)(xz + (size_t)(tok - (CONVK - 1) + j) * TWOE + ec);
      acc.x += xv.x * wt[0 * 4 + j];
      acc.y += xv.y * wt[1 * 4 + j];
      acc.z += xv.z * wt[2 * 4 + j];
      acc.w += xv.w * wt[3 * 4 + j];
    }
  }
  float4 s;
  s.x = acc.x / (1.f + __expf(-acc.x));
  s.y = acc.y / (1.f + __expf(-acc.y));
  s.z = acc.z / (1.f + __expf(-acc.z));
  s.w = acc.w / (1.f + __expf(-acc.w));
  *(float4*)(u + (size_t)idx * 4) = s;
  ushort4 r;
  r.x = f2bf(s.x); r.y = f2bf(s.y); r.z = f2bf(s.z); r.w = f2bf(s.w);
  *(ushort4*)(ubf + (size_t)idx * 4) = r;
}

// ---------------- chunked selective scan, 4 n-states per lane ----------------
// Block = 256 threads = 64 e's x 4 lanes; lane quad owns n = nq*4..nq*4+3.
// Grid = BATCH * (EDIM/EBLK) * CH.

// Pass 1: local scan with h_in=0; outputs hend, aprod=exp(A*sum dv) (float4).
__global__ __launch_bounds__(256) void scan_p1(
    const float* __restrict__ delta, const float* __restrict__ u,
    const float* __restrict__ xdbl, const float* __restrict__ A_log,
    float* __restrict__ hend, float* __restrict__ aprod) {
  const int tid = threadIdx.x;
  const int g = tid >> 2, nq = tid & 3;
  const int nch = blockIdx.x & (CH - 1);
  const int rem = blockIdx.x >> 3;
  const int e0 = (rem % (EDIM / EBLK)) * EBLK;
  const int b = rem / (EDIM / EBLK);
  const int e = e0 + g;
  float4 Al = *(const float4*)(A_log + (size_t)e * NSTATE + nq * 4);
  float4 A4;
  A4.x = -__expf(Al.x); A4.y = -__expf(Al.y);
  A4.z = -__expf(Al.z); A4.w = -__expf(Al.w);
  const size_t base = (size_t)b * SEQ + nch * CL;

  __shared__ float s_dv[2][8][EBLK];
  __shared__ float s_uv[2][8][EBLK];
  __shared__ float s_B[2][8][16];

  const float* gp0 = nullptr; float* ld0 = nullptr; size_t st0 = 0; int off0 = 0;
  const float* gp1 = nullptr; float* ld1 = nullptr; size_t st1 = 0; int off1 = 0;
  if (tid < 128) {
    int j = tid >> 4, q = tid & 15;
    gp0 = delta + (base + j) * EDIM + e0 + q * 4; st0 = 8 * (size_t)EDIM;
    ld0 = &s_dv[0][j][q * 4]; off0 = 8 * EBLK;
    if (tid < 32) {
      int jj = tid >> 2, nn = (tid & 3) * 4;
      gp1 = xdbl + (base + jj) * RN2 + RDIM + nn; st1 = 8 * (size_t)RN2;
      ld1 = &s_B[0][jj][nn]; off1 = 8 * 16;
    }
  } else {
    int r = tid - 128;
    int j = r >> 4, q = r & 15;
    gp0 = u + (base + j) * EDIM + e0 + q * 4; st0 = 8 * (size_t)EDIM;
    ld0 = &s_uv[0][j][q * 4]; off0 = 8 * EBLK;
  }
  if (ld0) { float4 v = *(const float4*)gp0; gp0 += st0; *(float4*)ld0 = v; }
  if (ld1) { float4 v = *(const float4*)gp1; gp1 += st1; *(float4*)ld1 = v; }

  float4 h = {0.f, 0.f, 0.f, 0.f};
  float sdv = 0.f;
  for (int it = 0; it < CL / 8; ++it) {
    const int cur = it & 1;
    const bool hn = (it < CL / 8 - 1);
    float4 nv0, nv1;
    if (hn && ld0) { nv0 = *(const float4*)gp0; gp0 += st0; }
    if (hn && ld1) { nv1 = *(const float4*)gp1; gp1 += st1; }
    __syncthreads();
#pragma unroll
    for (int j = 0; j < 8; ++j) {
      float dv = s_dv[cur][j][g];
      float uv = s_uv[cur][j][g];
      float4 Bv = *(const float4*)&s_B[cur][j][nq * 4];
      float duv = dv * uv;
      h.x = __expf(dv * A4.x) * h.x + duv * Bv.x;
      h.y = __expf(dv * A4.y) * h.y + duv * Bv.y;
      h.z = __expf(dv * A4.z) * h.z + duv * Bv.z;
      h.w = __expf(dv * A4.w) * h.w + duv * Bv.w;
      sdv += dv;
    }
    if (hn && ld0) *(float4*)(ld0 + (cur ^ 1) * off0) = nv0;
    if (hn && ld1) *(float4*)(ld1 + (cur ^ 1) * off1) = nv1;
  }
  size_t o = (((size_t)b * CH + nch) * EDIM + e) * NSTATE + nq * 4;
  *(float4*)(hend + o) = h;
  float4 ap;
  ap.x = __expf(A4.x * sdv); ap.y = __expf(A4.y * sdv);
  ap.z = __expf(A4.z * sdv); ap.w = __expf(A4.w * sdv);
  *(float4*)(aprod + o) = ap;
}

// Combine: prefix over chunks -> h_in per chunk.
__global__ __launch_bounds__(256) void scan_comb(
    const float* __restrict__ hend, const float* __restrict__ aprod,
    float* __restrict__ hin) {
  int i = blockIdx.x * 256 + threadIdx.x;
  if (i >= BATCH * EDIM * NSTATE) return;
  int b = i / (EDIM * NSTATE);
  int en = i % (EDIM * NSTATE);
  float he[CH], ap[CH];
#pragma unroll
  for (int c = 0; c < CH; ++c) {
    size_t o = ((size_t)(b * CH + c)) * EDIM * NSTATE + en;
    he[c] = hend[o]; ap[c] = aprod[o];
  }
  float hv = 0.f;
#pragma unroll
  for (int c = 0; c < CH; ++c) {
    size_t o = ((size_t)(b * CH + c)) * EDIM * NSTATE + en;
    hin[o] = hv;
    hv = he[c] + ap[c] * hv;
  }
}

// Pass 2: scan seeded with h_in; quad-reduced output, deferred epilogue.
__global__ __launch_bounds__(256) void scan_p2(
    const float* __restrict__ delta, const float* __restrict__ u,
    const float* __restrict__ xdbl, const float* __restrict__ xz,
    const float* __restrict__ A_log, const float* __restrict__ D_ssm,
    const float* __restrict__ hin, unsigned short* __restrict__ y) {
  const int tid = threadIdx.x;
  const int g = tid >> 2, nq = tid & 3;
  const int nch = blockIdx.x & (CH - 1);
  const int rem = blockIdx.x >> 3;
  const int e0 = (rem % (EDIM / EBLK)) * EBLK;
  const int b = rem / (EDIM / EBLK);
  const int e = e0 + g;
  float4 Al = *(const float4*)(A_log + (size_t)e * NSTATE + nq * 4);
  float4 A4;
  A4.x = -__expf(Al.x); A4.y = -__expf(Al.y);
  A4.z = -__expf(Al.z); A4.w = -__expf(Al.w);
  const float Dv = D_ssm[e];
  const size_t base = (size_t)b * SEQ + nch * CL;

  __shared__ float s_dv[2][8][EBLK];
  __shared__ float s_uv[2][8][EBLK];
  __shared__ float s_rs[2][8][EBLK];
  __shared__ float s_B[2][8][16];
  __shared__ float s_C[2][8][16];

  const float* gp0 = nullptr; float* ld0 = nullptr; size_t st0 = 0; int off0 = 0;
  const float* gp1 = nullptr; float* ld1 = nullptr; size_t st1 = 0; int off1 = 0;
  if (tid < 128) {
    int j = tid >> 4, q = tid & 15;
    gp0 = delta + (base + j) * EDIM + e0 + q * 4; st0 = 8 * (size_t)EDIM;
    ld0 = &s_dv[0][j][q * 4]; off0 = 8 * EBLK;
    gp1 = xz + (base + j) * TWOE + EDIM + e0 + q * 4; st1 = 8 * (size_t)TWOE;
    ld1 = &s_rs[0][j][q * 4]; off1 = 8 * EBLK;
  } else {
    int r = tid - 128;
    int j = r >> 4, q = r & 15;
    gp0 = u + (base + j) * EDIM + e0 + q * 4; st0 = 8 * (size_t)EDIM;
    ld0 = &s_uv[0][j][q * 4]; off0 = 8 * EBLK;
    if (r < 32) {
      int jj = r >> 2, nn = (r & 3) * 4;
      gp1 = xdbl + (base + jj) * RN2 + RDIM + nn; st1 = 8 * (size_t)RN2;
      ld1 = &s_B[0][jj][nn]; off1 = 8 * 16;
    } else if (r < 64) {
      int r2 = r - 32;
      int jj = r2 >> 2, nn = (r2 & 3) * 4;
      gp1 = xdbl + (base + jj) * RN2 + RDIM + NSTATE + nn; st1 = 8 * (size_t)RN2;
      ld1 = &s_C[0][jj][nn]; off1 = 8 * 16;
    }
  }
  if (ld0) { float4 v = *(const float4*)gp0; gp0 += st0; *(float4*)ld0 = v; }
  if (ld1) { float4 v = *(const float4*)gp1; gp1 += st1; *(float4*)ld1 = v; }

  float4 h = *(const float4*)(hin + (((size_t)b * CH + nch) * EDIM + e) * NSTATE + nq * 4);
  float pva = 0.f, pvb = 0.f;
  unsigned short* yp = y + base * EDIM + e;
  for (int it = 0; it < CL / 8; ++it) {
    const int cur = it & 1;
    const bool hn = (it < CL / 8 - 1);
    float4 nv0, nv1;
    if (hn && ld0) { nv0 = *(const float4*)gp0; gp0 += st0; }
    if (hn && ld1) { nv1 = *(const float4*)gp1; gp1 += st1; }
    __syncthreads();
#pragma unroll
    for (int j = 0; j < 8; ++j) {
      float dv = s_dv[cur][j][g];
      float uv = s_uv[cur][j][g];
      float4 Bv = *(const float4*)&s_B[cur][j][nq * 4];
      float4 Cv = *(const float4*)&s_C[cur][j][nq * 4];
      float duv = dv * uv;
      h.x = __expf(dv * A4.x) * h.x + duv * Bv.x;
      h.y = __expf(dv * A4.y) * h.y + duv * Bv.y;
      h.z = __expf(dv * A4.z) * h.z + duv * Bv.z;
      h.w = __expf(dv * A4.w) * h.w + duv * Bv.w;
      float p = h.x * Cv.x + h.y * Cv.y + h.z * Cv.z + h.w * Cv.w;
      p += __shfl_xor(p, 1);
      p += __shfl_xor(p, 2);
      pva = (j == nq) ? p : pva;
      pvb = (j == nq + 4) ? p : pvb;
    }
    // epilogue: lane nq emits steps it*8+nq and it*8+nq+4 (all lanes active)
    {
      float uv0 = s_uv[cur][nq][g],     rs0 = s_rs[cur][nq][g];
      float uv1 = s_uv[cur][nq + 4][g], rs1 = s_rs[cur][nq + 4][g];
      float sil0 = rs0 / (1.f + __expf(-rs0));
      float sil1 = rs1 / (1.f + __expf(-rs1));
      yp[(size_t)(it * 8 + nq) * EDIM]     = f2bf((pva + uv0 * Dv) * sil0);
      yp[(size_t)(it * 8 + nq + 4) * EDIM] = f2bf((pvb + uv1 * Dv) * sil1);
    }
    if (hn && ld0) *(float4*)(ld0 + (cur ^ 1) * off0) = nv0;
    if (hn && ld1) *(float4*)(ld1 + (cur ^ 1) * off1) = nv1;
  }
}

// Final: rmsnorm(last token) -> dot out_w -> sigmoid
__global__ __launch_bounds__(256) void final_k(
    const float* __restrict__ h, const float* __restrict__ nw,
    const float* __restrict__ ow, const float* __restrict__ ob,
    float* __restrict__ out) {
  const int b = blockIdx.x;
  const float* row = h + ((size_t)(b * SEQ + SEQ - 1)) * DMODEL;
  __shared__ float ls[8];
  __shared__ float ls2[8];
  const int lane = threadIdx.x & 63, wave = threadIdx.x >> 6;
  float s = 0.f;
  for (int i = threadIdx.x; i < DMODEL; i += 256) { float v = row[i]; s += v * v; }
  for (int off = 32; off; off >>= 1) s += __shfl_down(s, off);
  if (lane == 0) ls[wave] = s;
  __syncthreads();
  float tot = ls[0] + ls[1] + ls[2] + ls[3];
  float rs = rsqrtf(tot / (float)DMODEL + 1e-5f);
  float d = 0.f;
  for (int i = threadIdx.x; i < DMODEL; i += 256)
    d += row[i] * rs * nw[i] * ow[i];
  for (int off = 32; off; off >>= 1) d += __shfl_down(d, off);
  if (lane == 0) ls2[wave] = d;
  __syncthreads();
  if (threadIdx.x == 0) {
    float dot = ls2[0] + ls2[1] + ls2[2] + ls2[3] + ob[0];
    out[b] = 1.f / (1.f + expf(-dot));
  }
}

extern "C" void kernel_launch(void* const* d_in, const int* in_sizes, int n_in,
                              void* d_out, int out_size, void* d_ws, size_t ws_size,
                              hipStream_t stream) {
  const float* x         = (const float*)d_in[0];
  const float* in_w      = (const float*)d_in[1];
  const float* in_b      = (const float*)d_in[2];
  const float* in_proj_w = (const float*)d_in[3];
  const float* conv_w    = (const float*)d_in[4];
  const float* conv_b    = (const float*)d_in[5];
  const float* xproj_w   = (const float*)d_in[6];
  const float* dtproj_w  = (const float*)d_in[7];
  const float* dtproj_b  = (const float*)d_in[8];
  const float* A_log     = (const float*)d_in[9];
  const float* D_ssm     = (const float*)d_in[10];
  const float* outproj_w = (const float*)d_in[11];
  const float* norm_w    = (const float*)d_in[12];
  const float* normf_w   = (const float*)d_in[13];
  const float* out_w     = (const float*)d_in[14];
  const float* out_b     = (const float*)d_in[15];
  float* out = (float*)d_out;
  float* ws  = (float*)d_ws;

  // fp32 buffers
  float* h     = ws;                              // TOK*DMODEL
  float* xz    = h + (size_t)TOK * DMODEL;        // TOK*TWOE
  float* u     = xz + (size_t)TOK * TWOE;         // TOK*EDIM
  float* xdb   = u + (size_t)TOK * EDIM;          // TOK*RN2
  float* dl    = xdb + (size_t)TOK * RN2;         // TOK*EDIM
  float* part  = dl + (size_t)TOK * EDIM;         // XSPLIT*TOK*RN2
  float* hend  = part + (size_t)XSPLIT * TOK * RN2;
  float* aprod = hend + (size_t)BATCH * CH * EDIM * NSTATE;
  float* hin   = aprod + (size_t)BATCH * CH * EDIM * NSTATE;
  // bf16 buffers
  unsigned short* xn_bf = (unsigned short*)(hin + (size_t)BATCH * CH * EDIM * NSTATE);
  unsigned short* y_bf  = xn_bf + (size_t)TOK * DMODEL;
  unsigned short* u_bf  = y_bf + (size_t)TOK * EDIM;
  unsigned short* w_in  = u_bf + (size_t)TOK * EDIM;     // TWOE*DMODEL
  unsigned short* w_out = w_in + (size_t)TWOE * DMODEL;  // DMODEL*EDIM
  unsigned short* w_x   = w_out + (size_t)DMODEL * EDIM; // 128*EDIM (80 filled)
  unsigned short* dt_bf = w_x + (size_t)128 * EDIM;      // TOK*64
  unsigned short* w_dt  = dt_bf + (size_t)TOK * 64;      // EDIM*64

  dim3 blk(256);

  gemm_tn<EPI_BIAS><<<dim3(DMODEL / 64, TOK / 64), blk, 0, stream>>>(
      x, 32, in_w, 32, in_b, h, DMODEL, TOK, DMODEL, 32);

  for (int l = 0; l < 4; ++l) {
    rmsnorm_k<<<TOK, 256, 0, stream>>>(h, norm_w + l * DMODEL, xn_bf, DMODEL);

    cast_bf16_k<<<(TWOE * DMODEL / 4 + 255) / 256, 256, 0, stream>>>(
        in_proj_w + (size_t)l * TWOE * DMODEL, w_in, TWOE * DMODEL);

    gemm_mfma<128, 128, EPI_STORE, false><<<dim3(TWOE / 128, TOK / 128, 1), blk, 0, stream>>>(
        xn_bf, w_in, xz, TWOE, DMODEL, DMODEL, TWOE, 0, nullptr);

    conv_silu4_k<<<(TOK * EDIM / 4) / 256, 256, 0, stream>>>(
        xz, conv_w + l * EDIM * CONVK, conv_b + l * EDIM, u, u_bf);

    cast_bf16_k<<<(RN2 * EDIM / 4 + 255) / 256, 256, 0, stream>>>(
        xproj_w + (size_t)l * RN2 * EDIM, w_x, RN2 * EDIM);
    gemm_mfma<64, 64, EPI_STORE, true><<<dim3(2, TOK / 64, XSPLIT), blk, 0, stream>>>(
        u_bf, w_x, part, RN2, EDIM / XSPLIT, EDIM, RN2, (size_t)TOK * RN2, nullptr);
    reduce_part_k<<<(TOK * RN2 / 4 + 255) / 256, 256, 0, stream>>>(part, xdb, dt_bf);

    cast_dtw_k<<<(EDIM * 64 / 4 + 255) / 256, 256, 0, stream>>>(
        dtproj_w + (size_t)l * EDIM * RDIM, w_dt);
    gemm_mfma<64, 64, EPI_BIAS_SOFTPLUS, false><<<dim3(EDIM / 64, TOK / 64, 1), blk, 0, stream>>>(
        dt_bf, w_dt, dl, EDIM, 64, 64, EDIM, 0, dtproj_b + l * EDIM);

    scan_p1<<<BATCH * (EDIM / EBLK) * CH, 256, 0, stream>>>(
        dl, u, xdb, A_log + (size_t)l * EDIM * NSTATE, hend, aprod);
    scan_comb<<<(BATCH * EDIM * NSTATE + 255) / 256, 256, 0, stream>>>(
        hend, aprod, hin);
    scan_p2<<<BATCH * (EDIM / EBLK) * CH, 256, 0, stream>>>(
        dl, u, xdb, xz, A_log + (size_t)l * EDIM * NSTATE, D_ssm + l * EDIM,
        hin, y_bf);

    cast_bf16_k<<<(DMODEL * EDIM / 4 + 255) / 256, 256, 0, stream>>>(
        outproj_w + (size_t)l * DMODEL * EDIM, w_out, DMODEL * EDIM);

    gemm_mfma<64, 64, EPI_ADD, false><<<dim3(DMODEL / 64, TOK / 64, 1), blk, 0, stream>>>(
        y_bf, w_out, h, DMODEL, EDIM, EDIM, DMODEL, 0, nullptr);
  }

  final_k<<<BATCH, 256, 0, stream>>>(h, normf_w, out_w, out_b, out);
}